// Round 4
// baseline (977.776 us; speedup 1.0000x reference)
//
#include <hip/hip_runtime.h>
#include <hip/hip_bf16.h>
#include <hip/hip_fp16.h>

typedef unsigned int u32;
typedef unsigned short u16;

// ---------- fp16 pack/unpack (1 v_cvt each) ----------
__device__ __forceinline__ u16 f2h(float f) { return __half_as_ushort(__float2half(f)); }
__device__ __forceinline__ float h2f(u16 u) { return __half2float(__ushort_as_half(u)); }
__device__ __forceinline__ u32 packh2(float a, float b) {
    return (u32)f2h(a) | ((u32)f2h(b) << 16);
}
__device__ __forceinline__ float hlo(u32 u) { return h2f((u16)(u & 0xffffu)); }
__device__ __forceinline__ float hhi(u32 u) { return h2f((u16)(u >> 16)); }

// ---------- int-width-agnostic index load (w64=1 -> int64 data on device) ----------
__device__ __forceinline__ int gidx(const void* p, long long i, int w64) {
    if (w64) return (int)((const long long*)p)[i];
    return ((const int*)p)[i];
}

// Detect whether integer inputs are int64 (odd int32 words all zero) or int32.
__global__ void detect_kernel(const int* __restrict__ edge_words, int* __restrict__ flag, int E) {
    __shared__ int anyNZ;
    if (threadIdx.x == 0) anyNZ = 0;
    __syncthreads();
    const long long totalWords = 2LL * E;
    const long long step = totalWords / 1024;
    int nz = 0;
    for (int i = 0; i < 4; ++i) {
        long long w = ((long long)(threadIdx.x * 4 + i) * step) | 1;
        if (w < totalWords) nz |= edge_words[w];
    }
    if (nz) atomicOr(&anyNZ, 1);
    __syncthreads();
    if (threadIdx.x == 0) flag[0] = anyNZ ? 0 : 1;
}

// ---------- zero-init scratch ----------
__global__ void init_kernel(int* __restrict__ offs, int* __restrict__ cursor,
                            float* __restrict__ pool, int n) {
    int i = blockIdx.x * 256 + threadIdx.x;
    if (i <= n) offs[i] = 0;
    if (i < n) cursor[i] = 0;
    if (i < 4096) pool[i] = 0.f;
}

// ---------- CSR build ----------
__global__ void hist_kernel(const void* __restrict__ edge, const int* __restrict__ flag,
                            int* __restrict__ deg, int E, int n) {
    int e = blockIdx.x * 256 + threadIdx.x;
    if (e < E) {
        int d = gidx(edge, (long long)E + e, flag[0]);
        if ((unsigned)d < (unsigned)n) atomicAdd(&deg[d], 1);
    }
}

__global__ void scanA(int* __restrict__ offs, int* __restrict__ blockSums, int n) {
    __shared__ int ts[256];
    const int ITEMS = 8;
    int base = blockIdx.x * 2048 + threadIdx.x * ITEMS;
    int v[ITEMS];
    int sum = 0;
#pragma unroll
    for (int i = 0; i < ITEMS; ++i) {
        int idx = base + i;
        v[i] = (idx < n) ? offs[idx] : 0;
        sum += v[i];
    }
    ts[threadIdx.x] = sum;
    __syncthreads();
    int incl = sum;
    for (int d = 1; d < 256; d <<= 1) {
        int y = 0;
        if (threadIdx.x >= (unsigned)d) y = ts[threadIdx.x - d];
        __syncthreads();
        incl += y;
        ts[threadIdx.x] = incl;
        __syncthreads();
    }
    int run = incl - sum;
#pragma unroll
    for (int i = 0; i < ITEMS; ++i) {
        int idx = base + i;
        if (idx < n) offs[idx] = run;
        run += v[i];
    }
    if (threadIdx.x == 255) blockSums[blockIdx.x] = incl;
}

__global__ void scanB(int* __restrict__ blockSums, int nb) {
    __shared__ int ts[256];
    int t = threadIdx.x;
    int v = (t < nb) ? blockSums[t] : 0;
    ts[t] = v;
    __syncthreads();
    int incl = v;
    for (int d = 1; d < 256; d <<= 1) {
        int y = 0;
        if (t >= d) y = ts[t - d];
        __syncthreads();
        incl += y;
        ts[t] = incl;
        __syncthreads();
    }
    if (t < nb) blockSums[t] = incl - v;
}

__global__ void scanC(int* __restrict__ offs, const int* __restrict__ blockSums, int n, int total) {
    int base = blockIdx.x * 2048 + threadIdx.x * 8;
    int add = blockSums[blockIdx.x];
#pragma unroll
    for (int i = 0; i < 8; ++i) {
        int idx = base + i;
        if (idx < n) offs[idx] += add;
    }
    if (blockIdx.x == 0 && threadIdx.x == 0) offs[n] = total;
}

__global__ void scatter_kernel(const void* __restrict__ edge, const int* __restrict__ flag,
                               const int* __restrict__ offs, int* __restrict__ cursor,
                               int* __restrict__ ss, int E, int n) {
    int e = blockIdx.x * 256 + threadIdx.x;
    if (e < E) {
        int w64 = flag[0];
        int d = gidx(edge, (long long)E + e, w64);
        int s = gidx(edge, e, w64);
        if ((unsigned)d < (unsigned)n) {
            if ((unsigned)s >= (unsigned)n) s = 0;
            int p = offs[d] + atomicAdd(&cursor[d], 1);
            ss[p] = s;
        }
    }
}

// ---------- layer-1 dense matmuls: Z = X@Wl (f16), R = X@Wr + b (f32) ----------
__global__ void __launch_bounds__(256) mm_kernel(const float* __restrict__ X,
                                                 const float* __restrict__ Wl,
                                                 const float* __restrict__ Wr,
                                                 const float* __restrict__ Bv,
                                                 u16* __restrict__ Z,
                                                 float* __restrict__ R, int n) {
    __shared__ float2 wlr[4096];  // [k][c] -> (Wl, Wr)
    __shared__ float bs[64];
    for (int i = threadIdx.x; i < 4096; i += 256)
        wlr[i] = make_float2(Wl[i], Wr[i]);
    if (threadIdx.x < 64) bs[threadIdx.x] = Bv[threadIdx.x];
    __syncthreads();
    const int lane = threadIdx.x & 63;
    int node = (blockIdx.x << 2) | (threadIdx.x >> 6);
    const int stride = gridDim.x << 2;
    for (; node < n; node += stride) {
        float xv = X[node * 64 + lane];
        float az = 0.f, ar = bs[lane];
#pragma unroll
        for (int k = 0; k < 64; ++k) {
            float a = __shfl(xv, k, 64);
            float2 w = wlr[k * 64 + lane];
            az += a * w.x;
            ar += a * w.y;
        }
        Z[node * 64 + lane] = f2h(az);
        R[node * 64 + lane] = ar;
    }
}

// ---------- 2-rows-per-load gather-mean: half0 = even neighbors, half1 = odd ----------
__device__ __forceinline__ float2 gather2(const u32* __restrict__ Z32,
                                          const int* __restrict__ ss,
                                          int off, int end, int half, int sub) {
    float2 acc = make_float2(0.f, 0.f);
    int k = off + half;
    while (k + 14 < end) {
        int s0 = ss[k];      int s1 = ss[k + 2];  int s2 = ss[k + 4];  int s3 = ss[k + 6];
        int s4 = ss[k + 8];  int s5 = ss[k + 10]; int s6 = ss[k + 12]; int s7 = ss[k + 14];
        u32 u0 = Z32[s0 * 32 + sub]; u32 u1 = Z32[s1 * 32 + sub];
        u32 u2 = Z32[s2 * 32 + sub]; u32 u3 = Z32[s3 * 32 + sub];
        u32 u4 = Z32[s4 * 32 + sub]; u32 u5 = Z32[s5 * 32 + sub];
        u32 u6 = Z32[s6 * 32 + sub]; u32 u7 = Z32[s7 * 32 + sub];
        acc.x += ((hlo(u0) + hlo(u1)) + (hlo(u2) + hlo(u3))) +
                 ((hlo(u4) + hlo(u5)) + (hlo(u6) + hlo(u7)));
        acc.y += ((hhi(u0) + hhi(u1)) + (hhi(u2) + hhi(u3))) +
                 ((hhi(u4) + hhi(u5)) + (hhi(u6) + hhi(u7)));
        k += 16;
    }
    for (; k < end; k += 2) {
        u32 u = Z32[ss[k] * 32 + sub];
        acc.x += hlo(u);
        acc.y += hhi(u);
    }
    acc.x += __shfl_xor(acc.x, 32, 64);
    acc.y += __shfl_xor(acc.y, 32, 64);
    return acc;
}

// ---------- fused: h = relu(mean + R); half0: Zout=h@Wl (f16), half1: Rout=h@Wr+b ----------
__global__ void __launch_bounds__(256) aggmm_kernel(const u16* __restrict__ Zin,
                                                    const float* __restrict__ Rin,
                                                    const int* __restrict__ offs,
                                                    const int* __restrict__ ss,
                                                    const float* __restrict__ Wl,
                                                    const float* __restrict__ Wr,
                                                    const float* __restrict__ Bv,
                                                    u16* __restrict__ Zout,
                                                    float* __restrict__ Rout, int n) {
    __shared__ uint2 wl[1024];  // [kk][sub]: (W[2kk][2s]|W[2kk][2s+1], W[2kk+1][2s]|W[2kk+1][2s+1]) f16
    __shared__ uint2 wr[1024];
    __shared__ float bs[64];
    for (int i = threadIdx.x; i < 1024; i += 256) {
        int kk = i >> 5, sub = i & 31;
        const float* pl = Wl + (kk * 2) * 64 + sub * 2;
        const float* pr = Wr + (kk * 2) * 64 + sub * 2;
        wl[i] = make_uint2(packh2(pl[0], pl[1]), packh2(pl[64], pl[65]));
        wr[i] = make_uint2(packh2(pr[0], pr[1]), packh2(pr[64], pr[65]));
    }
    if (threadIdx.x < 64) bs[threadIdx.x] = Bv[threadIdx.x];
    __syncthreads();

    const int lane = threadIdx.x & 63;
    const int half = lane >> 5, sub = lane & 31;
    const u32* Z32 = (const u32*)Zin;
    const float2* R2 = (const float2*)Rin;
    u32* Z32o = (u32*)Zout;
    float2* R2o = (float2*)Rout;
    const uint2* wp = half ? wr : wl;

    const int wid = blockIdx.x * 4 + (threadIdx.x >> 6);
    const int nw = gridDim.x * 4;
    for (int node = wid; node < n; node += nw) {
        const int off = offs[node], end = offs[node + 1];
        float2 acc = gather2(Z32, ss, off, end, half, sub);
        const int deg = end - off;
        const float rd = deg > 0 ? 1.f / (float)deg : 0.f;
        float2 r = R2[node * 32 + sub];
        float hx = fmaxf(acc.x * rd + r.x, 0.f);
        float hy = fmaxf(acc.y * rd + r.y, 0.f);
        float o0 = half ? bs[sub * 2] : 0.f;
        float o1 = half ? bs[sub * 2 + 1] : 0.f;
#pragma unroll
        for (int kk = 0; kk < 32; ++kk) {
            float a0 = __shfl(hx, kk, 64);   // h[2kk]
            float a1 = __shfl(hy, kk, 64);   // h[2kk+1]
            uint2 w = wp[kk * 32 + sub];
            o0 += a0 * hlo(w.x) + a1 * hlo(w.y);
            o1 += a0 * hhi(w.x) + a1 * hhi(w.y);
        }
        if (half == 0) Z32o[node * 32 + sub] = packh2(o0, o1);
        else           R2o[node * 32 + sub] = make_float2(o0, o1);
    }
}

// ---------- final layer: H = relu(mean + R) (f32) ----------
__global__ void __launch_bounds__(256) agg_kernel(const u16* __restrict__ Zin,
                                                  const float* __restrict__ Rin,
                                                  const int* __restrict__ offs,
                                                  const int* __restrict__ ss,
                                                  float* __restrict__ H, int n) {
    const int lane = threadIdx.x & 63;
    const int half = lane >> 5, sub = lane & 31;
    const u32* Z32 = (const u32*)Zin;
    const float2* R2 = (const float2*)Rin;
    float2* H2 = (float2*)H;
    const int wid = blockIdx.x * 4 + (threadIdx.x >> 6);
    const int nw = gridDim.x * 4;
    for (int node = wid; node < n; node += nw) {
        const int off = offs[node], end = offs[node + 1];
        float2 acc = gather2(Z32, ss, off, end, half, sub);
        const int deg = end - off;
        const float rd = deg > 0 ? 1.f / (float)deg : 0.f;
        float2 r = R2[node * 32 + sub];
        if (half == 0) {
            float vx = fmaxf(acc.x * rd + r.x, 0.f);
            float vy = fmaxf(acc.y * rd + r.y, 0.f);
            H2[node * 32 + sub] = make_float2(vx, vy);
        }
    }
}

// ---------- global mean pool (batch sorted): 4 waves/block, 256 rows/wave ----------
__global__ void pool_kernel(const float* __restrict__ H, const void* __restrict__ batch,
                            const int* __restrict__ flag, float* __restrict__ pool, int n) {
    const int lane = threadIdx.x & 63;
    const int wave = threadIdx.x >> 6;
    int start = (blockIdx.x * 4 + wave) * 256;
    int end = min(start + 256, n);
    if (start >= end) return;
    const int w64 = flag[0];
    float acc = 0.f;
    int cur = gidx(batch, start, w64) & 63;
    for (int i = start; i < end; ++i) {
        int g = gidx(batch, i, w64) & 63;
        if (g != cur) {
            atomicAdd(&pool[cur * 64 + lane], acc);
            acc = 0.f;
            cur = g;
        }
        acc += H[i * 64 + lane];
    }
    atomicAdd(&pool[cur * 64 + lane], acc);
}

// ---------- head MLP: out = relu(g@Wc1+bc1)@Wc2 + bc2 ----------
__global__ void head_kernel(const float* __restrict__ pool, const void* __restrict__ batch,
                            const int* __restrict__ flag,
                            const float* __restrict__ Wc1, const float* __restrict__ bc1,
                            const float* __restrict__ Wc2, const float* __restrict__ bc2,
                            float* __restrict__ out, int n) {
    __shared__ float gm[64 * 64];
    __shared__ float am[64 * 32];
    __shared__ int cnts[64];
    const int tid = threadIdx.x;  // 256
    const int w64 = flag[0];
    if (tid < 64) {
        int lo = 0, hi = n;
        while (lo < hi) { int mid = (lo + hi) >> 1; if (gidx(batch, mid, w64) < tid) lo = mid + 1; else hi = mid; }
        int lo2 = 0, hi2 = n;
        int v2 = tid + 1;
        while (lo2 < hi2) { int mid = (lo2 + hi2) >> 1; if (gidx(batch, mid, w64) < v2) lo2 = mid + 1; else hi2 = mid; }
        cnts[tid] = lo2 - lo;
    }
    __syncthreads();
    for (int i = tid; i < 4096; i += 256) {
        int g = i >> 6;
        float c = (float)(cnts[g] > 0 ? cnts[g] : 1);
        gm[i] = pool[i] / c;
    }
    __syncthreads();
    for (int i = tid; i < 64 * 32; i += 256) {
        int g = i >> 5, j = i & 31;
        float acc = bc1[j];
        for (int k = 0; k < 64; ++k) acc += gm[g * 64 + k] * Wc1[k * 32 + j];
        am[i] = acc > 0.f ? acc : 0.f;
    }
    __syncthreads();
    if (tid < 128) {
        int g = tid >> 1, o = tid & 1;
        float acc = bc2[o];
        for (int j = 0; j < 32; ++j) acc += am[g * 32 + j] * Wc2[j * 2 + o];
        out[tid] = acc;
    }
}

extern "C" void kernel_launch(void* const* d_in, const int* in_sizes, int n_in,
                              void* d_out, int out_size, void* d_ws, size_t ws_size,
                              hipStream_t stream) {
    const float* x   = (const float*)d_in[0];
    const void* edge = d_in[1];     // int32 or int64, auto-detected
    const void* batch = d_in[2];
    const float* W1l = (const float*)d_in[3];
    const float* b1  = (const float*)d_in[4];
    const float* W1r = (const float*)d_in[5];
    const float* W2l = (const float*)d_in[6];
    const float* b2  = (const float*)d_in[7];
    const float* W2r = (const float*)d_in[8];
    const float* W3l = (const float*)d_in[9];
    const float* b3  = (const float*)d_in[10];
    const float* W3r = (const float*)d_in[11];
    const float* Wc1 = (const float*)d_in[12];
    const float* bc1 = (const float*)d_in[13];
    const float* Wc2 = (const float*)d_in[14];
    const float* bc2 = (const float*)d_in[15];

    const int n = in_sizes[0] / 64;   // 100000
    const int E = in_sizes[1] / 2;    // 1600000

    char* w = (char*)d_ws;
    size_t o = 0;
    auto take = [&](size_t bytes) -> void* {
        void* p = w + o;
        o = (o + bytes + 511) & ~(size_t)511;
        return p;
    };
    int* flag      = (int*)take(sizeof(int));
    int* offs      = (int*)take((size_t)(n + 1) * sizeof(int));
    int* cursor    = (int*)take((size_t)n * sizeof(int));
    int* blockSums = (int*)take(256 * sizeof(int));
    int* ss        = (int*)take((size_t)E * sizeof(int));
    u16* ZA        = (u16*)take((size_t)n * 64 * sizeof(u16));
    u16* ZB        = (u16*)take((size_t)n * 64 * sizeof(u16));
    float* RA      = (float*)take((size_t)n * 64 * sizeof(float));
    float* RB      = (float*)take((size_t)n * 64 * sizeof(float));
    float* H       = (float*)take((size_t)n * 64 * sizeof(float));
    float* pool    = (float*)take(64 * 64 * sizeof(float));

    init_kernel<<<(n + 256) / 256, 256, 0, stream>>>(offs, cursor, pool, n);
    detect_kernel<<<1, 256, 0, stream>>>((const int*)edge, flag, E);

    // CSR build (reused by all 3 layers)
    hist_kernel<<<(E + 255) / 256, 256, 0, stream>>>(edge, flag, offs, E, n);
    const int nbScan = (n + 2047) / 2048;
    scanA<<<nbScan, 256, 0, stream>>>(offs, blockSums, n);
    scanB<<<1, 256, 0, stream>>>(blockSums, nbScan);
    scanC<<<nbScan, 256, 0, stream>>>(offs, blockSums, n, E);
    scatter_kernel<<<(E + 255) / 256, 256, 0, stream>>>(edge, flag, offs, cursor, ss, E, n);

    // layer 1 lift
    mm_kernel<<<1024, 256, 0, stream>>>(x, W1l, W1r, b1, ZA, RA, n);
    // layer 1 agg fused with layer 2 lift (persistent grid-stride)
    aggmm_kernel<<<2048, 256, 0, stream>>>(ZA, RA, offs, ss, W2l, W2r, b2, ZB, RB, n);
    // layer 2 agg fused with layer 3 lift
    aggmm_kernel<<<2048, 256, 0, stream>>>(ZB, RB, offs, ss, W3l, W3r, b3, ZA, RA, n);
    // layer 3 agg
    agg_kernel<<<2048, 256, 0, stream>>>(ZA, RA, offs, ss, H, n);

    // pool + head
    pool_kernel<<<(n + 1023) / 1024, 256, 0, stream>>>(H, batch, flag, pool, n);
    head_kernel<<<1, 256, 0, stream>>>(pool, batch, flag, Wc1, bc1, Wc2, bc2,
                                       (float*)d_out, n);
}

// Round 5
// 637.658 us; speedup vs baseline: 1.5334x; 1.5334x over previous
//
#include <hip/hip_runtime.h>
#include <hip/hip_bf16.h>
#include <hip/hip_fp16.h>

typedef unsigned int u32;
typedef unsigned short u16;

// ---------- fp16 pack/unpack ----------
__device__ __forceinline__ u16 f2h(float f) { return __half_as_ushort(__float2half(f)); }
__device__ __forceinline__ float h2f(u16 u) { return __half2float(__ushort_as_half(u)); }
__device__ __forceinline__ u32 packh2(float a, float b) {
    return (u32)f2h(a) | ((u32)f2h(b) << 16);
}
__device__ __forceinline__ float hlo(u32 u) { return h2f((u16)(u & 0xffffu)); }
__device__ __forceinline__ float hhi(u32 u) { return h2f((u16)(u >> 16)); }

// ---------- int-width-agnostic index load (w64=1 -> int64 data on device) ----------
__device__ __forceinline__ int gidx(const void* p, long long i, int w64) {
    if (w64) return (int)((const long long*)p)[i];
    return ((const int*)p)[i];
}

// Detect whether integer inputs are int64 (odd int32 words all zero) or int32.
__global__ void detect_kernel(const int* __restrict__ edge_words, int* __restrict__ flag, int E) {
    __shared__ int anyNZ;
    if (threadIdx.x == 0) anyNZ = 0;
    __syncthreads();
    const long long totalWords = 2LL * E;
    const long long step = totalWords / 1024;
    int nz = 0;
    for (int i = 0; i < 4; ++i) {
        long long w = ((long long)(threadIdx.x * 4 + i) * step) | 1;
        if (w < totalWords) nz |= edge_words[w];
    }
    if (nz) atomicOr(&anyNZ, 1);
    __syncthreads();
    if (threadIdx.x == 0) flag[0] = anyNZ ? 0 : 1;
}

// ---------- zero-init scratch ----------
__global__ void init_kernel(int* __restrict__ offs, float* __restrict__ pool, int n) {
    int i = blockIdx.x * 256 + threadIdx.x;
    if (i <= n) offs[i] = 0;
    if (i < 4096) pool[i] = 0.f;
}

// ---------- CSR build: hist also records per-edge rank (old value of the counter) ----------
__global__ void hist_kernel(const void* __restrict__ edge, const int* __restrict__ flag,
                            int* __restrict__ deg, int* __restrict__ rank, int E, int n) {
    int e = blockIdx.x * 256 + threadIdx.x;
    if (e < E) {
        int d = gidx(edge, (long long)E + e, flag[0]);
        rank[e] = ((unsigned)d < (unsigned)n) ? atomicAdd(&deg[d], 1) : -1;
    }
}

__global__ void scanA(int* __restrict__ offs, int* __restrict__ blockSums, int n) {
    __shared__ int ts[256];
    const int ITEMS = 8;
    int base = blockIdx.x * 2048 + threadIdx.x * ITEMS;
    int v[ITEMS];
    int sum = 0;
#pragma unroll
    for (int i = 0; i < ITEMS; ++i) {
        int idx = base + i;
        v[i] = (idx < n) ? offs[idx] : 0;
        sum += v[i];
    }
    ts[threadIdx.x] = sum;
    __syncthreads();
    int incl = sum;
    for (int d = 1; d < 256; d <<= 1) {
        int y = 0;
        if (threadIdx.x >= (unsigned)d) y = ts[threadIdx.x - d];
        __syncthreads();
        incl += y;
        ts[threadIdx.x] = incl;
        __syncthreads();
    }
    int run = incl - sum;
#pragma unroll
    for (int i = 0; i < ITEMS; ++i) {
        int idx = base + i;
        if (idx < n) offs[idx] = run;
        run += v[i];
    }
    if (threadIdx.x == 255) blockSums[blockIdx.x] = incl;
}

__global__ void scanB(int* __restrict__ blockSums, int nb) {
    __shared__ int ts[256];
    int t = threadIdx.x;
    int v = (t < nb) ? blockSums[t] : 0;
    ts[t] = v;
    __syncthreads();
    int incl = v;
    for (int d = 1; d < 256; d <<= 1) {
        int y = 0;
        if (t >= d) y = ts[t - d];
        __syncthreads();
        incl += y;
        ts[t] = incl;
        __syncthreads();
    }
    if (t < nb) blockSums[t] = incl - v;
}

__global__ void scanC(int* __restrict__ offs, const int* __restrict__ blockSums, int n, int total) {
    int base = blockIdx.x * 2048 + threadIdx.x * 8;
    int add = blockSums[blockIdx.x];
#pragma unroll
    for (int i = 0; i < 8; ++i) {
        int idx = base + i;
        if (idx < n) offs[idx] += add;
    }
    if (blockIdx.x == 0 && threadIdx.x == 0) offs[n] = total;
}

// scatter without atomics: position = offs[d] + rank[e]
__global__ void scatter_kernel(const void* __restrict__ edge, const int* __restrict__ flag,
                               const int* __restrict__ offs, const int* __restrict__ rank,
                               int* __restrict__ ss, int E, int n) {
    int e = blockIdx.x * 256 + threadIdx.x;
    if (e < E) {
        int w64 = flag[0];
        int d = gidx(edge, (long long)E + e, w64);
        int s = gidx(edge, e, w64);
        int r = rank[e];
        if ((unsigned)d < (unsigned)n && r >= 0) {
            if ((unsigned)s >= (unsigned)n) s = 0;
            ss[offs[d] + r] = s;
        }
    }
}

// ---------- dense per-node matmuls: Z = X@Wl (f16), R = X@Wr + b (f32) ----------
// X is f32 (layer 1) or f16 (layers 2,3)
template <typename T>
__global__ void __launch_bounds__(256) mm_kernel(const T* __restrict__ X,
                                                 const float* __restrict__ Wl,
                                                 const float* __restrict__ Wr,
                                                 const float* __restrict__ Bv,
                                                 u16* __restrict__ Z,
                                                 float* __restrict__ R, int n) {
    __shared__ float2 wlr[4096];  // [k][c] -> (Wl, Wr)
    __shared__ float bs[64];
    for (int i = threadIdx.x; i < 4096; i += 256)
        wlr[i] = make_float2(Wl[i], Wr[i]);
    if (threadIdx.x < 64) bs[threadIdx.x] = Bv[threadIdx.x];
    __syncthreads();
    const int lane = threadIdx.x & 63;
    int node = (blockIdx.x << 2) | (threadIdx.x >> 6);
    const int stride = gridDim.x << 2;
    for (; node < n; node += stride) {
        T raw = X[node * 64 + lane];
        float xv;
        if constexpr (sizeof(T) == 2) xv = h2f((u16)raw); else xv = (float)raw;
        float az = 0.f, ar = bs[lane];
#pragma unroll
        for (int k = 0; k < 64; ++k) {
            float a = __shfl(xv, k, 64);
            float2 w = wlr[k * 64 + lane];
            az += a * w.x;
            ar += a * w.y;
        }
        Z[node * 64 + lane] = f2h(az);
        R[node * 64 + lane] = ar;
    }
}

// ---------- aggregation: H = relu(mean_neighbors(Z) + R), fp16 rows, 2 rows/load ----------
__global__ void __launch_bounds__(256) agg_kernel(const u16* __restrict__ Zin,
                                                  const float* __restrict__ Rin,
                                                  const int* __restrict__ offs,
                                                  const int* __restrict__ ss,
                                                  u16* __restrict__ Hout, int n) {
    const int lane = threadIdx.x & 63;
    const int half = lane >> 5, sub = lane & 31;
    const u32* Z32 = (const u32*)Zin;
    const float2* R2 = (const float2*)Rin;
    u32* H32 = (u32*)Hout;
    const int node = (blockIdx.x << 2) | (threadIdx.x >> 6);
    if (node >= n) return;
    const int off = offs[node], end = offs[node + 1];
    const int deg = end - off;
    float2 acc = make_float2(0.f, 0.f);
    for (int base = off; base < end; base += 64) {
        const int cnt = min(64, end - base);
        const int li = lane < cnt ? lane : cnt - 1;
        const int idx = ss[base + li];      // one coalesced wave-wide index load
        const int nb = cnt >> 1;            // neighbor pairs; half h takes j = 2p+h
        int p = 0;
        while (p + 8 <= nb) {
            const int j = 2 * p + half;
            int s0 = __shfl(idx, j);      int s1 = __shfl(idx, j + 2);
            int s2 = __shfl(idx, j + 4);  int s3 = __shfl(idx, j + 6);
            int s4 = __shfl(idx, j + 8);  int s5 = __shfl(idx, j + 10);
            int s6 = __shfl(idx, j + 12); int s7 = __shfl(idx, j + 14);
            u32 u0 = Z32[s0 * 32 + sub]; u32 u1 = Z32[s1 * 32 + sub];
            u32 u2 = Z32[s2 * 32 + sub]; u32 u3 = Z32[s3 * 32 + sub];
            u32 u4 = Z32[s4 * 32 + sub]; u32 u5 = Z32[s5 * 32 + sub];
            u32 u6 = Z32[s6 * 32 + sub]; u32 u7 = Z32[s7 * 32 + sub];
            acc.x += ((hlo(u0) + hlo(u1)) + (hlo(u2) + hlo(u3))) +
                     ((hlo(u4) + hlo(u5)) + (hlo(u6) + hlo(u7)));
            acc.y += ((hhi(u0) + hhi(u1)) + (hhi(u2) + hhi(u3))) +
                     ((hhi(u4) + hhi(u5)) + (hhi(u6) + hhi(u7)));
            p += 8;
        }
        for (; p < nb; ++p) {
            int s = __shfl(idx, 2 * p + half);
            u32 u = Z32[s * 32 + sub];
            acc.x += hlo(u);
            acc.y += hhi(u);
        }
        if (cnt & 1) {  // odd leftover: count it exactly once (half1), uniform branch
            int s = __shfl(idx, cnt - 1);
            u32 u = Z32[s * 32 + sub];
            float m = half ? 1.f : 0.f;
            acc.x += m * hlo(u);
            acc.y += m * hhi(u);
        }
    }
    acc.x += __shfl_xor(acc.x, 32, 64);
    acc.y += __shfl_xor(acc.y, 32, 64);
    const float rd = deg > 0 ? 1.f / (float)deg : 0.f;
    float2 r = R2[node * 32 + sub];
    float vx = fmaxf(fmaf(acc.x, rd, r.x), 0.f);
    float vy = fmaxf(fmaf(acc.y, rd, r.y), 0.f);
    if (half == 0) H32[node * 32 + sub] = packh2(vx, vy);
}

// ---------- global mean pool (batch sorted): 64 rows/wave ----------
__global__ void pool_kernel(const u16* __restrict__ H, const void* __restrict__ batch,
                            const int* __restrict__ flag, float* __restrict__ pool, int n) {
    const int lane = threadIdx.x & 63;
    const int wave = threadIdx.x >> 6;
    int start = (blockIdx.x * 4 + wave) * 64;
    int end = min(start + 64, n);
    if (start >= end) return;
    const int w64 = flag[0];
    float acc = 0.f;
    int cur = gidx(batch, start, w64) & 63;
    for (int i = start; i < end; ++i) {
        int g = gidx(batch, i, w64) & 63;
        if (g != cur) {
            atomicAdd(&pool[cur * 64 + lane], acc);
            acc = 0.f;
            cur = g;
        }
        acc += h2f(H[i * 64 + lane]);
    }
    atomicAdd(&pool[cur * 64 + lane], acc);
}

// ---------- head MLP: out = relu(g@Wc1+bc1)@Wc2 + bc2 ----------
__global__ void head_kernel(const float* __restrict__ pool, const void* __restrict__ batch,
                            const int* __restrict__ flag,
                            const float* __restrict__ Wc1, const float* __restrict__ bc1,
                            const float* __restrict__ Wc2, const float* __restrict__ bc2,
                            float* __restrict__ out, int n) {
    __shared__ float gm[64 * 64];
    __shared__ float am[64 * 32];
    __shared__ int cnts[64];
    const int tid = threadIdx.x;  // 256
    const int w64 = flag[0];
    if (tid < 64) {
        int lo = 0, hi = n;
        while (lo < hi) { int mid = (lo + hi) >> 1; if (gidx(batch, mid, w64) < tid) lo = mid + 1; else hi = mid; }
        int lo2 = 0, hi2 = n;
        int v2 = tid + 1;
        while (lo2 < hi2) { int mid = (lo2 + hi2) >> 1; if (gidx(batch, mid, w64) < v2) lo2 = mid + 1; else hi2 = mid; }
        cnts[tid] = lo2 - lo;
    }
    __syncthreads();
    for (int i = tid; i < 4096; i += 256) {
        int g = i >> 6;
        float c = (float)(cnts[g] > 0 ? cnts[g] : 1);
        gm[i] = pool[i] / c;
    }
    __syncthreads();
    for (int i = tid; i < 64 * 32; i += 256) {
        int g = i >> 5, j = i & 31;
        float acc = bc1[j];
        for (int k = 0; k < 64; ++k) acc += gm[g * 64 + k] * Wc1[k * 32 + j];
        am[i] = acc > 0.f ? acc : 0.f;
    }
    __syncthreads();
    if (tid < 128) {
        int g = tid >> 1, o = tid & 1;
        float acc = bc2[o];
        for (int j = 0; j < 32; ++j) acc += am[g * 32 + j] * Wc2[j * 2 + o];
        out[tid] = acc;
    }
}

extern "C" void kernel_launch(void* const* d_in, const int* in_sizes, int n_in,
                              void* d_out, int out_size, void* d_ws, size_t ws_size,
                              hipStream_t stream) {
    const float* x   = (const float*)d_in[0];
    const void* edge = d_in[1];     // int32 or int64, auto-detected
    const void* batch = d_in[2];
    const float* W1l = (const float*)d_in[3];
    const float* b1  = (const float*)d_in[4];
    const float* W1r = (const float*)d_in[5];
    const float* W2l = (const float*)d_in[6];
    const float* b2  = (const float*)d_in[7];
    const float* W2r = (const float*)d_in[8];
    const float* W3l = (const float*)d_in[9];
    const float* b3  = (const float*)d_in[10];
    const float* W3r = (const float*)d_in[11];
    const float* Wc1 = (const float*)d_in[12];
    const float* bc1 = (const float*)d_in[13];
    const float* Wc2 = (const float*)d_in[14];
    const float* bc2 = (const float*)d_in[15];

    const int n = in_sizes[0] / 64;   // 100000
    const int E = in_sizes[1] / 2;    // 1600000

    char* w = (char*)d_ws;
    size_t o = 0;
    auto take = [&](size_t bytes) -> void* {
        void* p = w + o;
        o = (o + bytes + 511) & ~(size_t)511;
        return p;
    };
    int* flag      = (int*)take(sizeof(int));
    int* offs      = (int*)take((size_t)(n + 1) * sizeof(int));
    int* rank      = (int*)take((size_t)E * sizeof(int));
    int* blockSums = (int*)take(256 * sizeof(int));
    int* ss        = (int*)take((size_t)E * sizeof(int));
    u16* Z         = (u16*)take((size_t)n * 64 * sizeof(u16));
    float* R       = (float*)take((size_t)n * 64 * sizeof(float));
    u16* HA        = (u16*)take((size_t)n * 64 * sizeof(u16));
    u16* HB        = (u16*)take((size_t)n * 64 * sizeof(u16));
    float* pool    = (float*)take(64 * 64 * sizeof(float));

    init_kernel<<<(n + 256) / 256, 256, 0, stream>>>(offs, pool, n);
    detect_kernel<<<1, 256, 0, stream>>>((const int*)edge, flag, E);

    // CSR build (reused by all 3 layers)
    hist_kernel<<<(E + 255) / 256, 256, 0, stream>>>(edge, flag, offs, rank, E, n);
    const int nbScan = (n + 2047) / 2048;
    scanA<<<nbScan, 256, 0, stream>>>(offs, blockSums, n);
    scanB<<<1, 256, 0, stream>>>(blockSums, nbScan);
    scanC<<<nbScan, 256, 0, stream>>>(offs, blockSums, n, E);
    scatter_kernel<<<(E + 255) / 256, 256, 0, stream>>>(edge, flag, offs, rank, ss, E, n);

    const int nodeBlocks = (n + 3) / 4;
    // layer 1
    mm_kernel<float><<<1024, 256, 0, stream>>>(x, W1l, W1r, b1, Z, R, n);
    agg_kernel<<<nodeBlocks, 256, 0, stream>>>(Z, R, offs, ss, HA, n);
    // layer 2
    mm_kernel<u16><<<1024, 256, 0, stream>>>(HA, W2l, W2r, b2, Z, R, n);
    agg_kernel<<<nodeBlocks, 256, 0, stream>>>(Z, R, offs, ss, HB, n);
    // layer 3
    mm_kernel<u16><<<1024, 256, 0, stream>>>(HB, W3l, W3r, b3, Z, R, n);
    agg_kernel<<<nodeBlocks, 256, 0, stream>>>(Z, R, offs, ss, HA, n);

    // pool + head
    pool_kernel<<<(n + 255) / 256, 256, 0, stream>>>(HA, batch, flag, pool, n);
    head_kernel<<<1, 256, 0, stream>>>(pool, batch, flag, Wc1, bc1, Wc2, bc2,
                                       (float*)d_out, n);
}

// Round 6
// 443.303 us; speedup vs baseline: 2.2057x; 1.4384x over previous
//
#include <hip/hip_runtime.h>
#include <hip/hip_bf16.h>
#include <hip/hip_fp16.h>

typedef unsigned int u32;
typedef unsigned short u16;
typedef _Float16 f16x8 __attribute__((ext_vector_type(8)));
typedef float f32x4 __attribute__((ext_vector_type(4)));

// ---------- fp16 pack/unpack ----------
__device__ __forceinline__ u16 f2h(float f) { return __half_as_ushort(__float2half(f)); }
__device__ __forceinline__ float h2f(u16 u) { return __half2float(__ushort_as_half(u)); }
__device__ __forceinline__ u32 packh2(float a, float b) {
    return (u32)f2h(a) | ((u32)f2h(b) << 16);
}
__device__ __forceinline__ float hlo(u32 u) { return h2f((u16)(u & 0xffffu)); }
__device__ __forceinline__ float hhi(u32 u) { return h2f((u16)(u >> 16)); }

// ---------- int-width-agnostic index load (w64=1 -> int64 data on device) ----------
__device__ __forceinline__ int gidx(const void* p, long long i, int w64) {
    if (w64) return (int)((const long long*)p)[i];
    return ((const int*)p)[i];
}

// Detect whether integer inputs are int64 (odd int32 words all zero) or int32.
__global__ void detect_kernel(const int* __restrict__ edge_words, int* __restrict__ flag, int E) {
    __shared__ int anyNZ;
    if (threadIdx.x == 0) anyNZ = 0;
    __syncthreads();
    const long long totalWords = 2LL * E;
    const long long step = totalWords / 1024;
    int nz = 0;
    for (int i = 0; i < 4; ++i) {
        long long w = ((long long)(threadIdx.x * 4 + i) * step) | 1;
        if (w < totalWords) nz |= edge_words[w];
    }
    if (nz) atomicOr(&anyNZ, 1);
    __syncthreads();
    if (threadIdx.x == 0) flag[0] = anyNZ ? 0 : 1;
}

// ---------- zero-init scratch ----------
__global__ void init_kernel(int* __restrict__ offs, float* __restrict__ pool, int n) {
    int i = blockIdx.x * 256 + threadIdx.x;
    if (i <= n) offs[i] = 0;
    if (i < 4096) pool[i] = 0.f;
}

// ---------- CSR build: hist also records per-edge rank (old value of the counter) ----------
__global__ void hist_kernel(const void* __restrict__ edge, const int* __restrict__ flag,
                            int* __restrict__ deg, int* __restrict__ rank, int E, int n) {
    int e = blockIdx.x * 256 + threadIdx.x;
    if (e < E) {
        int d = gidx(edge, (long long)E + e, flag[0]);
        rank[e] = ((unsigned)d < (unsigned)n) ? atomicAdd(&deg[d], 1) : -1;
    }
}

__global__ void scanA(int* __restrict__ offs, int* __restrict__ blockSums, int n) {
    __shared__ int ts[256];
    const int ITEMS = 8;
    int base = blockIdx.x * 2048 + threadIdx.x * ITEMS;
    int v[ITEMS];
    int sum = 0;
#pragma unroll
    for (int i = 0; i < ITEMS; ++i) {
        int idx = base + i;
        v[i] = (idx < n) ? offs[idx] : 0;
        sum += v[i];
    }
    ts[threadIdx.x] = sum;
    __syncthreads();
    int incl = sum;
    for (int d = 1; d < 256; d <<= 1) {
        int y = 0;
        if (threadIdx.x >= (unsigned)d) y = ts[threadIdx.x - d];
        __syncthreads();
        incl += y;
        ts[threadIdx.x] = incl;
        __syncthreads();
    }
    int run = incl - sum;
#pragma unroll
    for (int i = 0; i < ITEMS; ++i) {
        int idx = base + i;
        if (idx < n) offs[idx] = run;
        run += v[i];
    }
    if (threadIdx.x == 255) blockSums[blockIdx.x] = incl;
}

__global__ void scanB(int* __restrict__ blockSums, int nb) {
    __shared__ int ts[256];
    int t = threadIdx.x;
    int v = (t < nb) ? blockSums[t] : 0;
    ts[t] = v;
    __syncthreads();
    int incl = v;
    for (int d = 1; d < 256; d <<= 1) {
        int y = 0;
        if (t >= d) y = ts[t - d];
        __syncthreads();
        incl += y;
        ts[t] = incl;
        __syncthreads();
    }
    if (t < nb) blockSums[t] = incl - v;
}

__global__ void scanC(int* __restrict__ offs, const int* __restrict__ blockSums, int n, int total) {
    int base = blockIdx.x * 2048 + threadIdx.x * 8;
    int add = blockSums[blockIdx.x];
#pragma unroll
    for (int i = 0; i < 8; ++i) {
        int idx = base + i;
        if (idx < n) offs[idx] += add;
    }
    if (blockIdx.x == 0 && threadIdx.x == 0) offs[n] = total;
}

// scatter without atomics: position = offs[d] + rank[e]
__global__ void scatter_kernel(const void* __restrict__ edge, const int* __restrict__ flag,
                               const int* __restrict__ offs, const int* __restrict__ rank,
                               int* __restrict__ ss, int E, int n) {
    int e = blockIdx.x * 256 + threadIdx.x;
    if (e < E) {
        int w64 = flag[0];
        int d = gidx(edge, (long long)E + e, w64);
        int s = gidx(edge, e, w64);
        int r = rank[e];
        if ((unsigned)d < (unsigned)n && r >= 0) {
            if ((unsigned)s >= (unsigned)n) s = 0;
            ss[offs[d] + r] = s;
        }
    }
}

// ---------- MFMA lift: Z = X@Wl (f16), R = X@Wr + b (f16) ----------
// One wave computes a 16-node x 64-ch tile for BOTH Wl and Wr.
// Frag maps (gfx950 16x16x32): A[m=lane&15][k=quad*8+j]; B[k=quad*8+j][n=lane&15];
// C/D: col=lane&15, row=quad*4+reg.
template <typename T>  // T = float (layer 1) or u16/f16 (layers 2,3)
__global__ void __launch_bounds__(256) mm_mfma_kernel(const T* __restrict__ X,
                                                      const float* __restrict__ Wl,
                                                      const float* __restrict__ Wr,
                                                      const float* __restrict__ Bv,
                                                      u16* __restrict__ Z,
                                                      u16* __restrict__ R, int n) {
    const int lane = threadIdx.x & 63;
    const int quad = lane >> 4;
    const int m16 = lane & 15;

    // Weight fragments in registers (converted to f16 once per wave).
    f16x8 bl[2][4], br[2][4];
#pragma unroll
    for (int kh = 0; kh < 2; ++kh)
#pragma unroll
        for (int t = 0; t < 4; ++t) {
#pragma unroll
            for (int j = 0; j < 8; ++j) {
                int k = kh * 32 + quad * 8 + j;
                int c = t * 16 + m16;
                bl[kh][t][j] = (_Float16)Wl[k * 64 + c];
                br[kh][t][j] = (_Float16)Wr[k * 64 + c];
            }
        }
    float bias_t[4];
#pragma unroll
    for (int t = 0; t < 4; ++t) bias_t[t] = Bv[t * 16 + m16];

    const int ntiles = (n + 15) >> 4;
    const int nwaves = gridDim.x * 4;
    for (int tile = blockIdx.x * 4 + (threadIdx.x >> 6); tile < ntiles; tile += nwaves) {
        const int nodeBase = tile << 4;
        int nodeA = nodeBase + m16;
        if (nodeA >= n) nodeA = n - 1;
        f16x8 a[2];
        if constexpr (sizeof(T) == 2) {
            const _Float16* xp = (const _Float16*)X + (size_t)nodeA * 64;
#pragma unroll
            for (int kh = 0; kh < 2; ++kh)
                a[kh] = *(const f16x8*)(xp + kh * 32 + quad * 8);
        } else {
#pragma unroll
            for (int kh = 0; kh < 2; ++kh) {
                const float4* p = (const float4*)((const float*)X + (size_t)nodeA * 64 + kh * 32 + quad * 8);
                float4 x0 = p[0], x1 = p[1];
                a[kh][0] = (_Float16)x0.x; a[kh][1] = (_Float16)x0.y;
                a[kh][2] = (_Float16)x0.z; a[kh][3] = (_Float16)x0.w;
                a[kh][4] = (_Float16)x1.x; a[kh][5] = (_Float16)x1.y;
                a[kh][6] = (_Float16)x1.z; a[kh][7] = (_Float16)x1.w;
            }
        }
        f32x4 cl[4], cr[4];
#pragma unroll
        for (int t = 0; t < 4; ++t) {
            f32x4 c0 = {0.f, 0.f, 0.f, 0.f};
            c0 = __builtin_amdgcn_mfma_f32_16x16x32_f16(a[0], bl[0][t], c0, 0, 0, 0);
            c0 = __builtin_amdgcn_mfma_f32_16x16x32_f16(a[1], bl[1][t], c0, 0, 0, 0);
            cl[t] = c0;
            f32x4 c1 = {0.f, 0.f, 0.f, 0.f};
            c1 = __builtin_amdgcn_mfma_f32_16x16x32_f16(a[0], br[0][t], c1, 0, 0, 0);
            c1 = __builtin_amdgcn_mfma_f32_16x16x32_f16(a[1], br[1][t], c1, 0, 0, 0);
            cr[t] = c1;
        }
#pragma unroll
        for (int rg = 0; rg < 4; ++rg) {
            const int node = nodeBase + quad * 4 + rg;
            if (node < n) {
#pragma unroll
                for (int t = 0; t < 4; ++t) {
                    const int c = t * 16 + m16;
                    Z[(size_t)node * 64 + c] = f2h(cl[t][rg]);
                    R[(size_t)node * 64 + c] = f2h(cr[t][rg] + bias_t[t]);
                }
            }
        }
    }
}

// ---------- aggregation: H = relu(mean_neighbors(Z) + R), fp16 rows, 2 rows/load ----------
__global__ void __launch_bounds__(256) agg_kernel(const u16* __restrict__ Zin,
                                                  const u16* __restrict__ Rin,
                                                  const int* __restrict__ offs,
                                                  const int* __restrict__ ss,
                                                  u16* __restrict__ Hout, int n) {
    const int lane = threadIdx.x & 63;
    const int half = lane >> 5, sub = lane & 31;
    const u32* Z32 = (const u32*)Zin;
    const u32* R32 = (const u32*)Rin;
    u32* H32 = (u32*)Hout;
    const int node = (blockIdx.x << 2) | (threadIdx.x >> 6);
    if (node >= n) return;
    const int off = offs[node], end = offs[node + 1];
    const int deg = end - off;
    float2 acc = make_float2(0.f, 0.f);
    for (int base = off; base < end; base += 64) {
        const int cnt = min(64, end - base);
        const int li = lane < cnt ? lane : cnt - 1;
        const int idx = ss[base + li];      // one coalesced wave-wide index load
        const int nb = cnt >> 1;            // neighbor pairs; half h takes j = 2p+h
        int p = 0;
        while (p + 8 <= nb) {
            const int j = 2 * p + half;
            int s0 = __shfl(idx, j);      int s1 = __shfl(idx, j + 2);
            int s2 = __shfl(idx, j + 4);  int s3 = __shfl(idx, j + 6);
            int s4 = __shfl(idx, j + 8);  int s5 = __shfl(idx, j + 10);
            int s6 = __shfl(idx, j + 12); int s7 = __shfl(idx, j + 14);
            u32 u0 = Z32[s0 * 32 + sub]; u32 u1 = Z32[s1 * 32 + sub];
            u32 u2 = Z32[s2 * 32 + sub]; u32 u3 = Z32[s3 * 32 + sub];
            u32 u4 = Z32[s4 * 32 + sub]; u32 u5 = Z32[s5 * 32 + sub];
            u32 u6 = Z32[s6 * 32 + sub]; u32 u7 = Z32[s7 * 32 + sub];
            acc.x += ((hlo(u0) + hlo(u1)) + (hlo(u2) + hlo(u3))) +
                     ((hlo(u4) + hlo(u5)) + (hlo(u6) + hlo(u7)));
            acc.y += ((hhi(u0) + hhi(u1)) + (hhi(u2) + hhi(u3))) +
                     ((hhi(u4) + hhi(u5)) + (hhi(u6) + hhi(u7)));
            p += 8;
        }
        for (; p < nb; ++p) {
            int s = __shfl(idx, 2 * p + half);
            u32 u = Z32[s * 32 + sub];
            acc.x += hlo(u);
            acc.y += hhi(u);
        }
        if (cnt & 1) {  // odd leftover: count it exactly once (half1), uniform branch
            int s = __shfl(idx, cnt - 1);
            u32 u = Z32[s * 32 + sub];
            float m = half ? 1.f : 0.f;
            acc.x += m * hlo(u);
            acc.y += m * hhi(u);
        }
    }
    acc.x += __shfl_xor(acc.x, 32, 64);
    acc.y += __shfl_xor(acc.y, 32, 64);
    const float rd = deg > 0 ? 1.f / (float)deg : 0.f;
    u32 rr = R32[node * 32 + sub];
    float vx = fmaxf(fmaf(acc.x, rd, hlo(rr)), 0.f);
    float vy = fmaxf(fmaf(acc.y, rd, hhi(rr)), 0.f);
    if (half == 0) H32[node * 32 + sub] = packh2(vx, vy);
}

// ---------- global mean pool (batch sorted): 64 rows/wave ----------
__global__ void pool_kernel(const u16* __restrict__ H, const void* __restrict__ batch,
                            const int* __restrict__ flag, float* __restrict__ pool, int n) {
    const int lane = threadIdx.x & 63;
    const int wave = threadIdx.x >> 6;
    int start = (blockIdx.x * 4 + wave) * 64;
    int end = min(start + 64, n);
    if (start >= end) return;
    const int w64 = flag[0];
    float acc = 0.f;
    int cur = gidx(batch, start, w64) & 63;
    for (int i = start; i < end; ++i) {
        int g = gidx(batch, i, w64) & 63;
        if (g != cur) {
            atomicAdd(&pool[cur * 64 + lane], acc);
            acc = 0.f;
            cur = g;
        }
        acc += h2f(H[i * 64 + lane]);
    }
    atomicAdd(&pool[cur * 64 + lane], acc);
}

// ---------- head MLP: out = relu(g@Wc1+bc1)@Wc2 + bc2 ----------
__global__ void head_kernel(const float* __restrict__ pool, const void* __restrict__ batch,
                            const int* __restrict__ flag,
                            const float* __restrict__ Wc1, const float* __restrict__ bc1,
                            const float* __restrict__ Wc2, const float* __restrict__ bc2,
                            float* __restrict__ out, int n) {
    __shared__ float gm[64 * 64];
    __shared__ float am[64 * 32];
    __shared__ int cnts[64];
    const int tid = threadIdx.x;  // 256
    const int w64 = flag[0];
    if (tid < 64) {
        int lo = 0, hi = n;
        while (lo < hi) { int mid = (lo + hi) >> 1; if (gidx(batch, mid, w64) < tid) lo = mid + 1; else hi = mid; }
        int lo2 = 0, hi2 = n;
        int v2 = tid + 1;
        while (lo2 < hi2) { int mid = (lo2 + hi2) >> 1; if (gidx(batch, mid, w64) < v2) lo2 = mid + 1; else hi2 = mid; }
        cnts[tid] = lo2 - lo;
    }
    __syncthreads();
    for (int i = tid; i < 4096; i += 256) {
        int g = i >> 6;
        float c = (float)(cnts[g] > 0 ? cnts[g] : 1);
        gm[i] = pool[i] / c;
    }
    __syncthreads();
    for (int i = tid; i < 64 * 32; i += 256) {
        int g = i >> 5, j = i & 31;
        float acc = bc1[j];
        for (int k = 0; k < 64; ++k) acc += gm[g * 64 + k] * Wc1[k * 32 + j];
        am[i] = acc > 0.f ? acc : 0.f;
    }
    __syncthreads();
    if (tid < 128) {
        int g = tid >> 1, o = tid & 1;
        float acc = bc2[o];
        for (int j = 0; j < 32; ++j) acc += am[g * 32 + j] * Wc2[j * 2 + o];
        out[tid] = acc;
    }
}

extern "C" void kernel_launch(void* const* d_in, const int* in_sizes, int n_in,
                              void* d_out, int out_size, void* d_ws, size_t ws_size,
                              hipStream_t stream) {
    const float* x   = (const float*)d_in[0];
    const void* edge = d_in[1];     // int32 or int64, auto-detected
    const void* batch = d_in[2];
    const float* W1l = (const float*)d_in[3];
    const float* b1  = (const float*)d_in[4];
    const float* W1r = (const float*)d_in[5];
    const float* W2l = (const float*)d_in[6];
    const float* b2  = (const float*)d_in[7];
    const float* W2r = (const float*)d_in[8];
    const float* W3l = (const float*)d_in[9];
    const float* b3  = (const float*)d_in[10];
    const float* W3r = (const float*)d_in[11];
    const float* Wc1 = (const float*)d_in[12];
    const float* bc1 = (const float*)d_in[13];
    const float* Wc2 = (const float*)d_in[14];
    const float* bc2 = (const float*)d_in[15];

    const int n = in_sizes[0] / 64;   // 100000
    const int E = in_sizes[1] / 2;    // 1600000

    char* w = (char*)d_ws;
    size_t o = 0;
    auto take = [&](size_t bytes) -> void* {
        void* p = w + o;
        o = (o + bytes + 511) & ~(size_t)511;
        return p;
    };
    int* flag      = (int*)take(sizeof(int));
    int* offs      = (int*)take((size_t)(n + 1) * sizeof(int));
    int* rank      = (int*)take((size_t)E * sizeof(int));
    int* blockSums = (int*)take(256 * sizeof(int));
    int* ss        = (int*)take((size_t)E * sizeof(int));
    u16* Z         = (u16*)take((size_t)n * 64 * sizeof(u16));
    u16* R         = (u16*)take((size_t)n * 64 * sizeof(u16));
    u16* HA        = (u16*)take((size_t)n * 64 * sizeof(u16));
    u16* HB        = (u16*)take((size_t)n * 64 * sizeof(u16));
    float* pool    = (float*)take(64 * 64 * sizeof(float));

    init_kernel<<<(n + 256) / 256, 256, 0, stream>>>(offs, pool, n);
    detect_kernel<<<1, 256, 0, stream>>>((const int*)edge, flag, E);

    // CSR build (reused by all 3 layers)
    hist_kernel<<<(E + 255) / 256, 256, 0, stream>>>(edge, flag, offs, rank, E, n);
    const int nbScan = (n + 2047) / 2048;
    scanA<<<nbScan, 256, 0, stream>>>(offs, blockSums, n);
    scanB<<<1, 256, 0, stream>>>(blockSums, nbScan);
    scanC<<<nbScan, 256, 0, stream>>>(offs, blockSums, n, E);
    scatter_kernel<<<(E + 255) / 256, 256, 0, stream>>>(edge, flag, offs, rank, ss, E, n);

    const int nodeBlocks = (n + 3) / 4;
    const int mmBlocks = 784;   // 3136 waves, ~2 tiles of 16 nodes per wave
    // layer 1
    mm_mfma_kernel<float><<<mmBlocks, 256, 0, stream>>>(x, W1l, W1r, b1, Z, R, n);
    agg_kernel<<<nodeBlocks, 256, 0, stream>>>(Z, R, offs, ss, HA, n);
    // layer 2
    mm_mfma_kernel<u16><<<mmBlocks, 256, 0, stream>>>(HA, W2l, W2r, b2, Z, R, n);
    agg_kernel<<<nodeBlocks, 256, 0, stream>>>(Z, R, offs, ss, HB, n);
    // layer 3
    mm_mfma_kernel<u16><<<mmBlocks, 256, 0, stream>>>(HB, W3l, W3r, b3, Z, R, n);
    agg_kernel<<<nodeBlocks, 256, 0, stream>>>(Z, R, offs, ss, HA, n);

    // pool + head
    pool_kernel<<<(n + 255) / 256, 256, 0, stream>>>(HA, batch, flag, pool, n);
    head_kernel<<<1, 256, 0, stream>>>(pool, batch, flag, Wc1, bc1, Wc2, bc2,
                                       (float*)d_out, n);
}

// Round 7
// 388.873 us; speedup vs baseline: 2.5144x; 1.1400x over previous
//
#include <hip/hip_runtime.h>
#include <hip/hip_bf16.h>
#include <hip/hip_fp16.h>

typedef unsigned int u32;
typedef unsigned short u16;
typedef _Float16 f16x8 __attribute__((ext_vector_type(8)));
typedef float f32x4 __attribute__((ext_vector_type(4)));

#define NBLK1 512   // pass-1 blocks (edge chunks)

// ---------- fp16 pack/unpack ----------
__device__ __forceinline__ u16 f2h(float f) { return __half_as_ushort(__float2half(f)); }
__device__ __forceinline__ float h2f(u16 u) { return __half2float(__ushort_as_half(u)); }
__device__ __forceinline__ u32 packh2(float a, float b) {
    return (u32)f2h(a) | ((u32)f2h(b) << 16);
}
__device__ __forceinline__ float hlo(u32 u) { return h2f((u16)(u & 0xffffu)); }
__device__ __forceinline__ float hhi(u32 u) { return h2f((u16)(u >> 16)); }

// ---------- int-width-agnostic index load (w64=1 -> int64 data on device) ----------
__device__ __forceinline__ int gidx(const void* p, long long i, int w64) {
    if (w64) return (int)((const long long*)p)[i];
    return ((const int*)p)[i];
}

// Detect whether integer inputs are int64 (odd int32 words all zero) or int32.
__global__ void detect_kernel(const int* __restrict__ edge_words, int* __restrict__ flag, int E) {
    __shared__ int anyNZ;
    if (threadIdx.x == 0) anyNZ = 0;
    __syncthreads();
    const long long totalWords = 2LL * E;
    const long long step = totalWords / 1024;
    int nz = 0;
    for (int i = 0; i < 4; ++i) {
        long long w = ((long long)(threadIdx.x * 4 + i) * step) | 1;
        if (w < totalWords) nz |= edge_words[w];
    }
    if (nz) atomicOr(&anyNZ, 1);
    __syncthreads();
    if (threadIdx.x == 0) flag[0] = anyNZ ? 0 : 1;
}

// ---------- zero-init pool ----------
__global__ void init_kernel(float* __restrict__ pool) {
    int i = blockIdx.x * 256 + threadIdx.x;
    if (i < 4096) pool[i] = 0.f;
}

// ================= CSR build: 2-level LDS counting sort (NO global atomics) ==========
// Pass 1a: per-chunk LDS histogram over coarse buckets (dst>>9); HG[b*NBLK1+blk] plain store.
// Requires nb1 <= 256 (n <= 131072).
__global__ void __launch_bounds__(256) p1_hist(const void* __restrict__ edge,
                                               const int* __restrict__ flag,
                                               u32* __restrict__ HG, int E, int n, int nb1) {
    __shared__ u32 h[256];
    const int tid = threadIdx.x;
    h[tid] = 0;
    __syncthreads();
    const int w64 = flag[0];
    const int chunk = (E + NBLK1 - 1) / NBLK1;
    const int s = blockIdx.x * chunk;
    const int e = min(s + chunk, E);
    for (int i = s + tid; i < e; i += 256) {
        int d = gidx(edge, (long long)E + i, w64);
        if ((unsigned)d >= (unsigned)n) d = 0;
        atomicAdd(&h[d >> 9], 1);
    }
    __syncthreads();
    for (int b = tid; b < nb1; b += 256) HG[b * NBLK1 + blockIdx.x] = h[b];
}

// flat exclusive scan over NS elements (NS <= 2048*256)
__global__ void scanA(u32* __restrict__ offs, u32* __restrict__ blockSums, int n) {
    __shared__ u32 ts[256];
    const int ITEMS = 8;
    int base = blockIdx.x * 2048 + threadIdx.x * ITEMS;
    u32 v[ITEMS];
    u32 sum = 0;
#pragma unroll
    for (int i = 0; i < ITEMS; ++i) {
        int idx = base + i;
        v[i] = (idx < n) ? offs[idx] : 0;
        sum += v[i];
    }
    ts[threadIdx.x] = sum;
    __syncthreads();
    u32 incl = sum;
    for (int d = 1; d < 256; d <<= 1) {
        u32 y = 0;
        if (threadIdx.x >= (unsigned)d) y = ts[threadIdx.x - d];
        __syncthreads();
        incl += y;
        ts[threadIdx.x] = incl;
        __syncthreads();
    }
    u32 run = incl - sum;
#pragma unroll
    for (int i = 0; i < ITEMS; ++i) {
        int idx = base + i;
        if (idx < n) offs[idx] = run;
        run += v[i];
    }
    if (threadIdx.x == 255) blockSums[blockIdx.x] = incl;
}

__global__ void scanB(u32* __restrict__ blockSums, int nb) {
    __shared__ u32 ts[256];
    int t = threadIdx.x;
    u32 v = (t < nb) ? blockSums[t] : 0;
    ts[t] = v;
    __syncthreads();
    u32 incl = v;
    for (int d = 1; d < 256; d <<= 1) {
        u32 y = 0;
        if (t >= d) y = ts[t - d];
        __syncthreads();
        incl += y;
        ts[t] = incl;
        __syncthreads();
    }
    if (t < nb) blockSums[t] = incl - v;
}

__global__ void scanC(u32* __restrict__ offs, const u32* __restrict__ blockSums, int n) {
    int base = blockIdx.x * 2048 + threadIdx.x * 8;
    u32 add = blockSums[blockIdx.x];
#pragma unroll
    for (int i = 0; i < 8; ++i) {
        int idx = base + i;
        if (idx < n) offs[idx] += add;
    }
}

// Pass 1b: replay chunk; rank via LDS atomics; write packed (dst&511)<<17|src to P.
__global__ void __launch_bounds__(256) p1_scatter(const void* __restrict__ edge,
                                                  const int* __restrict__ flag,
                                                  const u32* __restrict__ HG,
                                                  u32* __restrict__ P, int E, int n, int nb1) {
    __shared__ u32 base[256];
    __shared__ u32 cur[256];
    const int tid = threadIdx.x;
    cur[tid] = 0;
    if (tid < nb1) base[tid] = HG[tid * NBLK1 + blockIdx.x];
    for (int b = tid + 256; b < nb1; b += 256) base[b] = HG[b * NBLK1 + blockIdx.x];
    __syncthreads();
    const int w64 = flag[0];
    const int chunk = (E + NBLK1 - 1) / NBLK1;
    const int s = blockIdx.x * chunk;
    const int e = min(s + chunk, E);
    for (int i = s + tid; i < e; i += 256) {
        int d = gidx(edge, (long long)E + i, w64);
        if ((unsigned)d >= (unsigned)n) d = 0;
        int sv = gidx(edge, i, w64);
        if ((unsigned)sv >= (unsigned)n) sv = 0;
        const int b1 = d >> 9;
        u32 r = atomicAdd(&cur[b1], 1);
        P[base[b1] + r] = (u32)sv | ((u32)(d & 511) << 17);
    }
}

// Pass 2: one block per coarse bucket — fine hist(512), LDS scan, write offs + final ss.
__global__ void __launch_bounds__(256) p2_kernel(const u32* __restrict__ P,
                                                 const u32* __restrict__ HG,
                                                 u32* __restrict__ offs,
                                                 int* __restrict__ ss, int E, int n, int nb1) {
    __shared__ u32 h2[512];
    __shared__ u32 ts[256];
    const int tid = threadIdx.x;
    const int b = blockIdx.x;
    const int bs = (int)HG[b * NBLK1];
    const int be = (b + 1 < nb1) ? (int)HG[(b + 1) * NBLK1] : E;
    h2[tid] = 0;
    h2[tid + 256] = 0;
    __syncthreads();
    for (int i = bs + tid; i < be; i += 256) atomicAdd(&h2[(P[i] >> 17) & 511], 1);
    __syncthreads();
    // block-level exclusive scan over 512 bins (2 per thread)
    u32 v0 = h2[2 * tid], v1 = h2[2 * tid + 1];
    u32 sum = v0 + v1;
    ts[tid] = sum;
    __syncthreads();
    u32 incl = sum;
    for (int d = 1; d < 256; d <<= 1) {
        u32 y = 0;
        if (tid >= d) y = ts[tid - d];
        __syncthreads();
        incl += y;
        ts[tid] = incl;
        __syncthreads();
    }
    u32 run = incl - sum;
    h2[2 * tid] = run;
    h2[2 * tid + 1] = run + v0;
    const int node0 = b * 512 + 2 * tid;
    if (node0 < n) offs[node0] = bs + run;
    if (node0 + 1 < n) offs[node0 + 1] = bs + run + v0;
    if (b == 0 && tid == 0) offs[n] = (u32)E;
    __syncthreads();
    // scatter src into final CSR slot (h2 doubles as cursor)
    for (int i = bs + tid; i < be; i += 256) {
        u32 p = P[i];
        u32 r = atomicAdd(&h2[(p >> 17) & 511], 1);
        ss[bs + r] = (int)(p & 0x1FFFFu);
    }
}

// ---------- MFMA lift: Z = X@Wl (f16), R = X@Wr + b (f16) ----------
template <typename T>  // T = float (layer 1) or u16/f16 (layers 2,3)
__global__ void __launch_bounds__(256) mm_mfma_kernel(const T* __restrict__ X,
                                                      const float* __restrict__ Wl,
                                                      const float* __restrict__ Wr,
                                                      const float* __restrict__ Bv,
                                                      u16* __restrict__ Z,
                                                      u16* __restrict__ R, int n) {
    const int lane = threadIdx.x & 63;
    const int quad = lane >> 4;
    const int m16 = lane & 15;

    f16x8 bl[2][4], br[2][4];
#pragma unroll
    for (int kh = 0; kh < 2; ++kh)
#pragma unroll
        for (int t = 0; t < 4; ++t) {
#pragma unroll
            for (int j = 0; j < 8; ++j) {
                int k = kh * 32 + quad * 8 + j;
                int c = t * 16 + m16;
                bl[kh][t][j] = (_Float16)Wl[k * 64 + c];
                br[kh][t][j] = (_Float16)Wr[k * 64 + c];
            }
        }
    float bias_t[4];
#pragma unroll
    for (int t = 0; t < 4; ++t) bias_t[t] = Bv[t * 16 + m16];

    const int ntiles = (n + 15) >> 4;
    const int nwaves = gridDim.x * 4;
    for (int tile = blockIdx.x * 4 + (threadIdx.x >> 6); tile < ntiles; tile += nwaves) {
        const int nodeBase = tile << 4;
        int nodeA = nodeBase + m16;
        if (nodeA >= n) nodeA = n - 1;
        f16x8 a[2];
        if constexpr (sizeof(T) == 2) {
            const _Float16* xp = (const _Float16*)X + (size_t)nodeA * 64;
#pragma unroll
            for (int kh = 0; kh < 2; ++kh)
                a[kh] = *(const f16x8*)(xp + kh * 32 + quad * 8);
        } else {
#pragma unroll
            for (int kh = 0; kh < 2; ++kh) {
                const float4* p = (const float4*)((const float*)X + (size_t)nodeA * 64 + kh * 32 + quad * 8);
                float4 x0 = p[0], x1 = p[1];
                a[kh][0] = (_Float16)x0.x; a[kh][1] = (_Float16)x0.y;
                a[kh][2] = (_Float16)x0.z; a[kh][3] = (_Float16)x0.w;
                a[kh][4] = (_Float16)x1.x; a[kh][5] = (_Float16)x1.y;
                a[kh][6] = (_Float16)x1.z; a[kh][7] = (_Float16)x1.w;
            }
        }
        f32x4 cl[4], cr[4];
#pragma unroll
        for (int t = 0; t < 4; ++t) {
            f32x4 c0 = {0.f, 0.f, 0.f, 0.f};
            c0 = __builtin_amdgcn_mfma_f32_16x16x32_f16(a[0], bl[0][t], c0, 0, 0, 0);
            c0 = __builtin_amdgcn_mfma_f32_16x16x32_f16(a[1], bl[1][t], c0, 0, 0, 0);
            cl[t] = c0;
            f32x4 c1 = {0.f, 0.f, 0.f, 0.f};
            c1 = __builtin_amdgcn_mfma_f32_16x16x32_f16(a[0], br[0][t], c1, 0, 0, 0);
            c1 = __builtin_amdgcn_mfma_f32_16x16x32_f16(a[1], br[1][t], c1, 0, 0, 0);
            cr[t] = c1;
        }
#pragma unroll
        for (int rg = 0; rg < 4; ++rg) {
            const int node = nodeBase + quad * 4 + rg;
            if (node < n) {
#pragma unroll
                for (int t = 0; t < 4; ++t) {
                    const int c = t * 16 + m16;
                    Z[(size_t)node * 64 + c] = f2h(cl[t][rg]);
                    R[(size_t)node * 64 + c] = f2h(cr[t][rg] + bias_t[t]);
                }
            }
        }
    }
}

// ---------- aggregation: H = relu(mean_neighbors(Z) + R), fp16 rows, 2 rows/load ----------
__global__ void __launch_bounds__(256) agg_kernel(const u16* __restrict__ Zin,
                                                  const u16* __restrict__ Rin,
                                                  const u32* __restrict__ offs,
                                                  const int* __restrict__ ss,
                                                  u16* __restrict__ Hout, int n) {
    const int lane = threadIdx.x & 63;
    const int half = lane >> 5, sub = lane & 31;
    const u32* Z32 = (const u32*)Zin;
    const u32* R32 = (const u32*)Rin;
    u32* H32 = (u32*)Hout;
    const int node = (blockIdx.x << 2) | (threadIdx.x >> 6);
    if (node >= n) return;
    const int off = (int)offs[node], end = (int)offs[node + 1];
    const int deg = end - off;
    float2 acc = make_float2(0.f, 0.f);
    for (int base = off; base < end; base += 64) {
        const int cnt = min(64, end - base);
        const int li = lane < cnt ? lane : cnt - 1;
        const int idx = ss[base + li];      // one coalesced wave-wide index load
        const int nb = cnt >> 1;            // neighbor pairs; half h takes j = 2p+h
        int p = 0;
        while (p + 8 <= nb) {
            const int j = 2 * p + half;
            int s0 = __shfl(idx, j);      int s1 = __shfl(idx, j + 2);
            int s2 = __shfl(idx, j + 4);  int s3 = __shfl(idx, j + 6);
            int s4 = __shfl(idx, j + 8);  int s5 = __shfl(idx, j + 10);
            int s6 = __shfl(idx, j + 12); int s7 = __shfl(idx, j + 14);
            u32 u0 = Z32[s0 * 32 + sub]; u32 u1 = Z32[s1 * 32 + sub];
            u32 u2 = Z32[s2 * 32 + sub]; u32 u3 = Z32[s3 * 32 + sub];
            u32 u4 = Z32[s4 * 32 + sub]; u32 u5 = Z32[s5 * 32 + sub];
            u32 u6 = Z32[s6 * 32 + sub]; u32 u7 = Z32[s7 * 32 + sub];
            acc.x += ((hlo(u0) + hlo(u1)) + (hlo(u2) + hlo(u3))) +
                     ((hlo(u4) + hlo(u5)) + (hlo(u6) + hlo(u7)));
            acc.y += ((hhi(u0) + hhi(u1)) + (hhi(u2) + hhi(u3))) +
                     ((hhi(u4) + hhi(u5)) + (hhi(u6) + hhi(u7)));
            p += 8;
        }
        for (; p < nb; ++p) {
            int s = __shfl(idx, 2 * p + half);
            u32 u = Z32[s * 32 + sub];
            acc.x += hlo(u);
            acc.y += hhi(u);
        }
        if (cnt & 1) {  // odd leftover: count it exactly once (half1), uniform branch
            int s = __shfl(idx, cnt - 1);
            u32 u = Z32[s * 32 + sub];
            float m = half ? 1.f : 0.f;
            acc.x += m * hlo(u);
            acc.y += m * hhi(u);
        }
    }
    acc.x += __shfl_xor(acc.x, 32, 64);
    acc.y += __shfl_xor(acc.y, 32, 64);
    const float rd = deg > 0 ? 1.f / (float)deg : 0.f;
    u32 rr = R32[node * 32 + sub];
    float vx = fmaxf(fmaf(acc.x, rd, hlo(rr)), 0.f);
    float vy = fmaxf(fmaf(acc.y, rd, hhi(rr)), 0.f);
    if (half == 0) H32[node * 32 + sub] = packh2(vx, vy);
}

// ---------- global mean pool (batch sorted): 64 rows/wave ----------
__global__ void pool_kernel(const u16* __restrict__ H, const void* __restrict__ batch,
                            const int* __restrict__ flag, float* __restrict__ pool, int n) {
    const int lane = threadIdx.x & 63;
    const int wave = threadIdx.x >> 6;
    int start = (blockIdx.x * 4 + wave) * 64;
    int end = min(start + 64, n);
    if (start >= end) return;
    const int w64 = flag[0];
    float acc = 0.f;
    int cur = gidx(batch, start, w64) & 63;
    for (int i = start; i < end; ++i) {
        int g = gidx(batch, i, w64) & 63;
        if (g != cur) {
            atomicAdd(&pool[cur * 64 + lane], acc);
            acc = 0.f;
            cur = g;
        }
        acc += h2f(H[i * 64 + lane]);
    }
    atomicAdd(&pool[cur * 64 + lane], acc);
}

// ---------- head MLP: out = relu(g@Wc1+bc1)@Wc2 + bc2 ----------
__global__ void head_kernel(const float* __restrict__ pool, const void* __restrict__ batch,
                            const int* __restrict__ flag,
                            const float* __restrict__ Wc1, const float* __restrict__ bc1,
                            const float* __restrict__ Wc2, const float* __restrict__ bc2,
                            float* __restrict__ out, int n) {
    __shared__ float gm[64 * 64];
    __shared__ float am[64 * 32];
    __shared__ int cnts[64];
    const int tid = threadIdx.x;  // 256
    const int w64 = flag[0];
    if (tid < 64) {
        int lo = 0, hi = n;
        while (lo < hi) { int mid = (lo + hi) >> 1; if (gidx(batch, mid, w64) < tid) lo = mid + 1; else hi = mid; }
        int lo2 = 0, hi2 = n;
        int v2 = tid + 1;
        while (lo2 < hi2) { int mid = (lo2 + hi2) >> 1; if (gidx(batch, mid, w64) < v2) lo2 = mid + 1; else hi2 = mid; }
        cnts[tid] = lo2 - lo;
    }
    __syncthreads();
    for (int i = tid; i < 4096; i += 256) {
        int g = i >> 6;
        float c = (float)(cnts[g] > 0 ? cnts[g] : 1);
        gm[i] = pool[i] / c;
    }
    __syncthreads();
    for (int i = tid; i < 64 * 32; i += 256) {
        int g = i >> 5, j = i & 31;
        float acc = bc1[j];
        for (int k = 0; k < 64; ++k) acc += gm[g * 64 + k] * Wc1[k * 32 + j];
        am[i] = acc > 0.f ? acc : 0.f;
    }
    __syncthreads();
    if (tid < 128) {
        int g = tid >> 1, o = tid & 1;
        float acc = bc2[o];
        for (int j = 0; j < 32; ++j) acc += am[g * 32 + j] * Wc2[j * 2 + o];
        out[tid] = acc;
    }
}

extern "C" void kernel_launch(void* const* d_in, const int* in_sizes, int n_in,
                              void* d_out, int out_size, void* d_ws, size_t ws_size,
                              hipStream_t stream) {
    const float* x   = (const float*)d_in[0];
    const void* edge = d_in[1];     // int32 or int64, auto-detected
    const void* batch = d_in[2];
    const float* W1l = (const float*)d_in[3];
    const float* b1  = (const float*)d_in[4];
    const float* W1r = (const float*)d_in[5];
    const float* W2l = (const float*)d_in[6];
    const float* b2  = (const float*)d_in[7];
    const float* W2r = (const float*)d_in[8];
    const float* W3l = (const float*)d_in[9];
    const float* b3  = (const float*)d_in[10];
    const float* W3r = (const float*)d_in[11];
    const float* Wc1 = (const float*)d_in[12];
    const float* bc1 = (const float*)d_in[13];
    const float* Wc2 = (const float*)d_in[14];
    const float* bc2 = (const float*)d_in[15];

    const int n = in_sizes[0] / 64;   // 100000
    const int E = in_sizes[1] / 2;    // 1600000
    const int nb1 = (n + 511) >> 9;   // 196 coarse buckets (requires <= 256)
    const int NS = nb1 * NBLK1;       // scanned histogram length

    char* w = (char*)d_ws;
    size_t o = 0;
    auto take = [&](size_t bytes) -> void* {
        void* p = w + o;
        o = (o + bytes + 511) & ~(size_t)511;
        return p;
    };
    int* flag      = (int*)take(sizeof(int));
    u32* offs      = (u32*)take((size_t)(n + 1) * sizeof(u32));
    u32* HG        = (u32*)take((size_t)(NS + 1) * sizeof(u32));
    u32* blockSums = (u32*)take(256 * sizeof(u32));
    u32* P         = (u32*)take((size_t)E * sizeof(u32));
    int* ss        = (int*)take((size_t)E * sizeof(int));
    u16* Z         = (u16*)take((size_t)n * 64 * sizeof(u16));
    u16* R         = (u16*)take((size_t)n * 64 * sizeof(u16));
    u16* HA        = (u16*)take((size_t)n * 64 * sizeof(u16));
    u16* HB        = (u16*)take((size_t)n * 64 * sizeof(u16));
    float* pool    = (float*)take(64 * 64 * sizeof(float));

    init_kernel<<<16, 256, 0, stream>>>(pool);
    detect_kernel<<<1, 256, 0, stream>>>((const int*)edge, flag, E);

    // CSR build via 2-level counting sort (no global atomics)
    p1_hist<<<NBLK1, 256, 0, stream>>>(edge, flag, HG, E, n, nb1);
    const int nbScan = (NS + 2047) / 2048;
    scanA<<<nbScan, 256, 0, stream>>>(HG, blockSums, NS);
    scanB<<<1, 256, 0, stream>>>(blockSums, nbScan);
    scanC<<<nbScan, 256, 0, stream>>>(HG, blockSums, NS);
    p1_scatter<<<NBLK1, 256, 0, stream>>>(edge, flag, HG, P, E, n, nb1);
    p2_kernel<<<nb1, 256, 0, stream>>>(P, HG, offs, ss, E, n, nb1);

    const int nodeBlocks = (n + 3) / 4;
    const int mmBlocks = 784;
    // layer 1
    mm_mfma_kernel<float><<<mmBlocks, 256, 0, stream>>>(x, W1l, W1r, b1, Z, R, n);
    agg_kernel<<<nodeBlocks, 256, 0, stream>>>(Z, R, offs, ss, HA, n);
    // layer 2
    mm_mfma_kernel<u16><<<mmBlocks, 256, 0, stream>>>(HA, W2l, W2r, b2, Z, R, n);
    agg_kernel<<<nodeBlocks, 256, 0, stream>>>(Z, R, offs, ss, HB, n);
    // layer 3
    mm_mfma_kernel<u16><<<mmBlocks, 256, 0, stream>>>(HB, W3l, W3r, b3, Z, R, n);
    agg_kernel<<<nodeBlocks, 256, 0, stream>>>(Z, R, offs, ss, HA, n);

    // pool + head
    pool_kernel<<<(n + 255) / 256, 256, 0, stream>>>(HA, batch, flag, pool, n);
    head_kernel<<<1, 256, 0, stream>>>(pool, batch, flag, Wc1, bc1, Wc2, bc2,
                                       (float*)d_out, n);
}

// Round 8
// 353.492 us; speedup vs baseline: 2.7661x; 1.1001x over previous
//
#include <hip/hip_runtime.h>
#include <hip/hip_bf16.h>
#include <hip/hip_fp16.h>

typedef unsigned int u32;
typedef unsigned short u16;
typedef _Float16 f16x8 __attribute__((ext_vector_type(8)));
typedef float f32x4 __attribute__((ext_vector_type(4)));

#define NBLK1 512   // pass-1 blocks (edge chunks)
#define MMBLK 784   // mm blocks

// ---------- fp16 pack/unpack ----------
__device__ __forceinline__ u16 f2h(float f) { return __half_as_ushort(__float2half(f)); }
__device__ __forceinline__ u32 packh2(float a, float b) {
    return (u32)f2h(a) | ((u32)f2h(b) << 16);
}
__device__ __forceinline__ __half2 sx(__half2 v, int m) {
    int iv = __shfl_xor(*(int*)&v, m, 64);
    return *(__half2*)&iv;
}

// ---------- int-width-agnostic index load (w64=1 -> int64 data on device) ----------
__device__ __forceinline__ int gidx(const void* p, long long i, int w64) {
    if (w64) return (int)((const long long*)p)[i];
    return ((const int*)p)[i];
}

// ---------- init + detect (fused) ----------
__global__ void init_detect(const int* __restrict__ edge_words, int* __restrict__ flag,
                            u32* __restrict__ ticket, float* __restrict__ pool, int E) {
    const int tid = threadIdx.x;
    for (int i = tid; i < 4096; i += 256) pool[i] = 0.f;
    if (tid == 0) *ticket = 0;
    __shared__ int anyNZ;
    if (tid == 0) anyNZ = 0;
    __syncthreads();
    const long long totalWords = 2LL * E;
    const long long step = totalWords / 1024;
    int nz = 0;
    for (int i = 0; i < 4; ++i) {
        long long w = ((long long)(tid * 4 + i) * step) | 1;
        if (w < totalWords) nz |= edge_words[w];
    }
    if (nz) atomicOr(&anyNZ, 1);
    __syncthreads();
    if (tid == 0) flag[0] = anyNZ ? 0 : 1;
}

// ---------- fused: p1_hist (blocks < NBLK1) + layer-1 MFMA lift (rest) ----------
__global__ void __launch_bounds__(256) fused_hist_mm1(
        const void* __restrict__ edge, const int* __restrict__ flag,
        u32* __restrict__ HG, int E, int n, int nb1,
        const float* __restrict__ X, const float* __restrict__ Wl,
        const float* __restrict__ Wr, const float* __restrict__ Bv,
        u16* __restrict__ Z, u16* __restrict__ R) {
    if (blockIdx.x < NBLK1) {
        // ---- histogram over coarse buckets (dst>>9) ----
        __shared__ u32 h[256];
        const int tid = threadIdx.x;
        h[tid] = 0;
        __syncthreads();
        const int w64 = flag[0];
        const int chunk = (E + NBLK1 - 1) / NBLK1;
        const int s = blockIdx.x * chunk;
        const int e = min(s + chunk, E);
        for (int i = s + tid; i < e; i += 256) {
            int d = gidx(edge, (long long)E + i, w64);
            if ((unsigned)d >= (unsigned)n) d = 0;
            atomicAdd(&h[d >> 9], 1);
        }
        __syncthreads();
        for (int b = tid; b < nb1; b += 256) HG[b * NBLK1 + blockIdx.x] = h[b];
        return;
    }
    // ---- MFMA lift, layer 1 (f32 input) ----
    const int lane = threadIdx.x & 63;
    const int quad = lane >> 4;
    const int m16 = lane & 15;
    f16x8 bl[2][4], br[2][4];
#pragma unroll
    for (int kh = 0; kh < 2; ++kh)
#pragma unroll
        for (int t = 0; t < 4; ++t)
#pragma unroll
            for (int j = 0; j < 8; ++j) {
                int k = kh * 32 + quad * 8 + j;
                int c = t * 16 + m16;
                bl[kh][t][j] = (_Float16)Wl[k * 64 + c];
                br[kh][t][j] = (_Float16)Wr[k * 64 + c];
            }
    float bias_t[4];
#pragma unroll
    for (int t = 0; t < 4; ++t) bias_t[t] = Bv[t * 16 + m16];

    const int ntiles = (n + 15) >> 4;
    const int nwaves = (gridDim.x - NBLK1) * 4;
    for (int tile = (blockIdx.x - NBLK1) * 4 + (threadIdx.x >> 6); tile < ntiles; tile += nwaves) {
        const int nodeBase = tile << 4;
        int nodeA = nodeBase + m16;
        if (nodeA >= n) nodeA = n - 1;
        f16x8 a[2];
#pragma unroll
        for (int kh = 0; kh < 2; ++kh) {
            const float4* p = (const float4*)(X + (size_t)nodeA * 64 + kh * 32 + quad * 8);
            float4 x0 = p[0], x1 = p[1];
            a[kh][0] = (_Float16)x0.x; a[kh][1] = (_Float16)x0.y;
            a[kh][2] = (_Float16)x0.z; a[kh][3] = (_Float16)x0.w;
            a[kh][4] = (_Float16)x1.x; a[kh][5] = (_Float16)x1.y;
            a[kh][6] = (_Float16)x1.z; a[kh][7] = (_Float16)x1.w;
        }
        f32x4 cl[4], cr[4];
#pragma unroll
        for (int t = 0; t < 4; ++t) {
            f32x4 c0 = {0.f, 0.f, 0.f, 0.f};
            c0 = __builtin_amdgcn_mfma_f32_16x16x32_f16(a[0], bl[0][t], c0, 0, 0, 0);
            c0 = __builtin_amdgcn_mfma_f32_16x16x32_f16(a[1], bl[1][t], c0, 0, 0, 0);
            cl[t] = c0;
            f32x4 c1 = {0.f, 0.f, 0.f, 0.f};
            c1 = __builtin_amdgcn_mfma_f32_16x16x32_f16(a[0], br[0][t], c1, 0, 0, 0);
            c1 = __builtin_amdgcn_mfma_f32_16x16x32_f16(a[1], br[1][t], c1, 0, 0, 0);
            cr[t] = c1;
        }
#pragma unroll
        for (int rg = 0; rg < 4; ++rg) {
            const int node = nodeBase + quad * 4 + rg;
            if (node < n) {
#pragma unroll
                for (int t = 0; t < 4; ++t) {
                    const int c = t * 16 + m16;
                    Z[(size_t)node * 64 + c] = f2h(cl[t][rg]);
                    R[(size_t)node * 64 + c] = f2h(cr[t][rg] + bias_t[t]);
                }
            }
        }
    }
}

// ---------- scanA with fused scanB (ticketed last block) ----------
__global__ void scanAB(u32* __restrict__ HG, u32* __restrict__ blockSums,
                       u32* __restrict__ SB, u32* __restrict__ ticket, int n) {
    __shared__ u32 ts[256];
    __shared__ int isLast;
    const int ITEMS = 8;
    const int tid = threadIdx.x;
    int base = blockIdx.x * 2048 + tid * ITEMS;
    u32 v[ITEMS];
    u32 sum = 0;
#pragma unroll
    for (int i = 0; i < ITEMS; ++i) {
        int idx = base + i;
        v[i] = (idx < n) ? HG[idx] : 0;
        sum += v[i];
    }
    ts[tid] = sum;
    __syncthreads();
    u32 incl = sum;
    for (int d = 1; d < 256; d <<= 1) {
        u32 y = 0;
        if (tid >= d) y = ts[tid - d];
        __syncthreads();
        incl += y;
        ts[tid] = incl;
        __syncthreads();
    }
    u32 run = incl - sum;
#pragma unroll
    for (int i = 0; i < ITEMS; ++i) {
        int idx = base + i;
        if (idx < n) HG[idx] = run;
        run += v[i];
    }
    if (tid == 255) {
        atomicExch(&blockSums[blockIdx.x], incl);
        __threadfence();
        u32 t = atomicAdd(ticket, 1);
        isLast = (t == gridDim.x - 1);
    }
    __syncthreads();
    if (!isLast) return;
    // last block: exclusive-scan the per-block totals (atomic reads; device-scope safe)
    const int nb = gridDim.x;
    u32 bv = (tid < nb) ? atomicAdd(&blockSums[tid], 0u) : 0;
    ts[tid] = bv;
    __syncthreads();
    u32 bincl = bv;
    for (int d = 1; d < 256; d <<= 1) {
        u32 y = 0;
        if (tid >= d) y = ts[tid - d];
        __syncthreads();
        bincl += y;
        ts[tid] = bincl;
        __syncthreads();
    }
    if (tid < nb) SB[tid] = bincl - bv;
}

// ---------- pass 1b: rank via LDS atomics; write packed (dst&511)<<17|src ----------
__global__ void __launch_bounds__(256) p1_scatter(const void* __restrict__ edge,
                                                  const int* __restrict__ flag,
                                                  const u32* __restrict__ HG,
                                                  const u32* __restrict__ SB,
                                                  u32* __restrict__ P, int E, int n, int nb1) {
    __shared__ u32 base[256];
    __shared__ u32 cur[256];
    const int tid = threadIdx.x;
    cur[tid] = 0;
    for (int b = tid; b < nb1; b += 256) {
        int i = b * NBLK1 + blockIdx.x;
        base[b] = HG[i] + SB[i >> 11];
    }
    __syncthreads();
    const int w64 = flag[0];
    const int chunk = (E + NBLK1 - 1) / NBLK1;
    const int s = blockIdx.x * chunk;
    const int e = min(s + chunk, E);
    for (int i = s + tid; i < e; i += 256) {
        int d = gidx(edge, (long long)E + i, w64);
        if ((unsigned)d >= (unsigned)n) d = 0;
        int sv = gidx(edge, i, w64);
        if ((unsigned)sv >= (unsigned)n) sv = 0;
        const int b1 = d >> 9;
        u32 r = atomicAdd(&cur[b1], 1);
        P[base[b1] + r] = (u32)sv | ((u32)(d & 511) << 17);
    }
}

// ---------- pass 2: per coarse bucket — fine hist(512), LDS scan, offs + final ss ----------
__global__ void __launch_bounds__(256) p2_kernel(const u32* __restrict__ P,
                                                 const u32* __restrict__ HG,
                                                 const u32* __restrict__ SB,
                                                 u32* __restrict__ offs,
                                                 int* __restrict__ ss, int E, int n, int nb1) {
    __shared__ u32 h2[512];
    __shared__ u32 ts[256];
    const int tid = threadIdx.x;
    const int b = blockIdx.x;
    const int i0 = b * NBLK1;
    const int bs = (int)(HG[i0] + SB[i0 >> 11]);
    int be;
    if (b + 1 < nb1) {
        const int i1 = (b + 1) * NBLK1;
        be = (int)(HG[i1] + SB[i1 >> 11]);
    } else be = E;
    h2[tid] = 0;
    h2[tid + 256] = 0;
    __syncthreads();
    for (int i = bs + tid; i < be; i += 256) atomicAdd(&h2[(P[i] >> 17) & 511], 1);
    __syncthreads();
    u32 v0 = h2[2 * tid], v1 = h2[2 * tid + 1];
    u32 sum = v0 + v1;
    ts[tid] = sum;
    __syncthreads();
    u32 incl = sum;
    for (int d = 1; d < 256; d <<= 1) {
        u32 y = 0;
        if (tid >= d) y = ts[tid - d];
        __syncthreads();
        incl += y;
        ts[tid] = incl;
        __syncthreads();
    }
    u32 run = incl - sum;
    h2[2 * tid] = run;
    h2[2 * tid + 1] = run + v0;
    const int node0 = b * 512 + 2 * tid;
    if (node0 < n) offs[node0] = bs + run;
    if (node0 + 1 < n) offs[node0 + 1] = bs + run + v0;
    if (b == 0 && tid == 0) offs[n] = (u32)E;
    __syncthreads();
    for (int i = bs + tid; i < be; i += 256) {
        u32 p = P[i];
        u32 r = atomicAdd(&h2[(p >> 17) & 511], 1);
        ss[bs + r] = (int)(p & 0x1FFFFu);
    }
}

// ---------- MFMA lift (layers 2,3): Z = X@Wl (f16), R = X@Wr + b (f16) ----------
__global__ void __launch_bounds__(256) mm_mfma_kernel(const u16* __restrict__ X,
                                                      const float* __restrict__ Wl,
                                                      const float* __restrict__ Wr,
                                                      const float* __restrict__ Bv,
                                                      u16* __restrict__ Z,
                                                      u16* __restrict__ R, int n) {
    const int lane = threadIdx.x & 63;
    const int quad = lane >> 4;
    const int m16 = lane & 15;
    f16x8 bl[2][4], br[2][4];
#pragma unroll
    for (int kh = 0; kh < 2; ++kh)
#pragma unroll
        for (int t = 0; t < 4; ++t)
#pragma unroll
            for (int j = 0; j < 8; ++j) {
                int k = kh * 32 + quad * 8 + j;
                int c = t * 16 + m16;
                bl[kh][t][j] = (_Float16)Wl[k * 64 + c];
                br[kh][t][j] = (_Float16)Wr[k * 64 + c];
            }
    float bias_t[4];
#pragma unroll
    for (int t = 0; t < 4; ++t) bias_t[t] = Bv[t * 16 + m16];

    const int ntiles = (n + 15) >> 4;
    const int nwaves = gridDim.x * 4;
    for (int tile = blockIdx.x * 4 + (threadIdx.x >> 6); tile < ntiles; tile += nwaves) {
        const int nodeBase = tile << 4;
        int nodeA = nodeBase + m16;
        if (nodeA >= n) nodeA = n - 1;
        const _Float16* xp = (const _Float16*)X + (size_t)nodeA * 64;
        f16x8 a[2];
#pragma unroll
        for (int kh = 0; kh < 2; ++kh)
            a[kh] = *(const f16x8*)(xp + kh * 32 + quad * 8);
        f32x4 cl[4], cr[4];
#pragma unroll
        for (int t = 0; t < 4; ++t) {
            f32x4 c0 = {0.f, 0.f, 0.f, 0.f};
            c0 = __builtin_amdgcn_mfma_f32_16x16x32_f16(a[0], bl[0][t], c0, 0, 0, 0);
            c0 = __builtin_amdgcn_mfma_f32_16x16x32_f16(a[1], bl[1][t], c0, 0, 0, 0);
            cl[t] = c0;
            f32x4 c1 = {0.f, 0.f, 0.f, 0.f};
            c1 = __builtin_amdgcn_mfma_f32_16x16x32_f16(a[0], br[0][t], c1, 0, 0, 0);
            c1 = __builtin_amdgcn_mfma_f32_16x16x32_f16(a[1], br[1][t], c1, 0, 0, 0);
            cr[t] = c1;
        }
#pragma unroll
        for (int rg = 0; rg < 4; ++rg) {
            const int node = nodeBase + quad * 4 + rg;
            if (node < n) {
#pragma unroll
                for (int t = 0; t < 4; ++t) {
                    const int c = t * 16 + m16;
                    Z[(size_t)node * 64 + c] = f2h(cl[t][rg]);
                    R[(size_t)node * 64 + c] = f2h(cr[t][rg] + bias_t[t]);
                }
            }
        }
    }
}

// ---------- aggregation: packed-f16 accumulate, dwordx2 row loads (4 rows/instr) ----------
__global__ void __launch_bounds__(256) agg_kernel(const u16* __restrict__ Zin,
                                                  const u16* __restrict__ Rin,
                                                  const u32* __restrict__ offs,
                                                  const int* __restrict__ ss,
                                                  u16* __restrict__ Hout, int n) {
    const int lane = threadIdx.x & 63;
    const int q = lane >> 4;       // quarter handles rows j == q (mod 4)
    const int sub = lane & 15;     // 8-byte word-pair within a 128 B row
    const u32* Z32 = (const u32*)Zin;
    const int node = (blockIdx.x << 2) | (threadIdx.x >> 6);
    if (node >= n) return;
    const int off = (int)offs[node], end = (int)offs[node + 1];
    const int deg = end - off;
    const __half2 zero2 = __float2half2_rn(0.f);
    const __half2 one2 = __float2half2_rn(1.f);
    __half2 a0 = zero2, a1 = zero2, b0 = zero2, b1 = zero2;
    for (int base = off; base < end; base += 64) {
        const int cnt = min(64, end - base);
        const int idx = ss[base + (lane < cnt ? lane : cnt - 1)];
        const int nb8 = cnt >> 3;
        for (int p = 0; p < nb8; ++p) {
            int j0 = (p << 3) + q;
            int s0 = __shfl(idx, j0, 64);
            int s1 = __shfl(idx, j0 + 4, 64);
            uint2 u0 = *(const uint2*)(Z32 + s0 * 32 + 2 * sub);
            uint2 u1 = *(const uint2*)(Z32 + s1 * 32 + 2 * sub);
            a0 = __hadd2(a0, *(const __half2*)&u0.x);
            a1 = __hadd2(a1, *(const __half2*)&u0.y);
            b0 = __hadd2(b0, *(const __half2*)&u1.x);
            b1 = __hadd2(b1, *(const __half2*)&u1.y);
        }
        const int done = nb8 << 3;
        const int rem = cnt - done;   // 0..7
        if (rem) {
            int j = done + q;
            int s0 = __shfl(idx, j < cnt ? j : cnt - 1, 64);
            uint2 u0 = *(const uint2*)(Z32 + s0 * 32 + 2 * sub);
            __half2 m0 = (j < cnt) ? one2 : zero2;
            a0 = __hfma2(*(const __half2*)&u0.x, m0, a0);
            a1 = __hfma2(*(const __half2*)&u0.y, m0, a1);
            if (rem > 4) {
                int j2 = done + 4 + q;
                int s1 = __shfl(idx, j2 < cnt ? j2 : cnt - 1, 64);
                uint2 u1 = *(const uint2*)(Z32 + s1 * 32 + 2 * sub);
                __half2 m1 = (j2 < cnt) ? one2 : zero2;
                b0 = __hfma2(*(const __half2*)&u1.x, m1, b0);
                b1 = __hfma2(*(const __half2*)&u1.y, m1, b1);
            }
        }
    }
    a0 = __hadd2(a0, b0);
    a1 = __hadd2(a1, b1);
    a0 = __hadd2(a0, sx(a0, 16)); a0 = __hadd2(a0, sx(a0, 32));
    a1 = __hadd2(a1, sx(a1, 16)); a1 = __hadd2(a1, sx(a1, 32));
    if (q == 0) {
        const u32* R32 = (const u32*)Rin;
        uint2 rr = *(const uint2*)(R32 + node * 32 + 2 * sub);
        const float rd = deg > 0 ? 1.f / (float)deg : 0.f;
        float2 s01 = __half22float2(a0);
        float2 s23 = __half22float2(a1);
        float2 r01 = __half22float2(*(const __half2*)&rr.x);
        float2 r23 = __half22float2(*(const __half2*)&rr.y);
        uint2 outp;
        outp.x = packh2(fmaxf(fmaf(s01.x, rd, r01.x), 0.f),
                        fmaxf(fmaf(s01.y, rd, r01.y), 0.f));
        outp.y = packh2(fmaxf(fmaf(s23.x, rd, r23.x), 0.f),
                        fmaxf(fmaf(s23.y, rd, r23.y), 0.f));
        *(uint2*)(((u32*)Hout) + node * 32 + 2 * sub) = outp;
    }
}

// ---------- global mean pool (batch sorted): 64 rows/wave ----------
__global__ void pool_kernel(const u16* __restrict__ H, const void* __restrict__ batch,
                            const int* __restrict__ flag, float* __restrict__ pool, int n) {
    const int lane = threadIdx.x & 63;
    const int wave = threadIdx.x >> 6;
    int start = (blockIdx.x * 4 + wave) * 64;
    int end = min(start + 64, n);
    if (start >= end) return;
    const int w64 = flag[0];
    float acc = 0.f;
    int cur = gidx(batch, start, w64) & 63;
    for (int i = start; i < end; ++i) {
        int g = gidx(batch, i, w64) & 63;
        if (g != cur) {
            atomicAdd(&pool[cur * 64 + lane], acc);
            acc = 0.f;
            cur = g;
        }
        acc += __half2float(__ushort_as_half(H[i * 64 + lane]));
    }
    atomicAdd(&pool[cur * 64 + lane], acc);
}

// ---------- head MLP: out = relu(g@Wc1+bc1)@Wc2 + bc2 ----------
__global__ void head_kernel(const float* __restrict__ pool, const void* __restrict__ batch,
                            const int* __restrict__ flag,
                            const float* __restrict__ Wc1, const float* __restrict__ bc1,
                            const float* __restrict__ Wc2, const float* __restrict__ bc2,
                            float* __restrict__ out, int n) {
    __shared__ float gm[64 * 64];
    __shared__ float am[64 * 32];
    __shared__ int cnts[64];
    const int tid = threadIdx.x;  // 256
    const int w64 = flag[0];
    if (tid < 64) {
        int lo = 0, hi = n;
        while (lo < hi) { int mid = (lo + hi) >> 1; if (gidx(batch, mid, w64) < tid) lo = mid + 1; else hi = mid; }
        int lo2 = 0, hi2 = n;
        int v2 = tid + 1;
        while (lo2 < hi2) { int mid = (lo2 + hi2) >> 1; if (gidx(batch, mid, w64) < v2) lo2 = mid + 1; else hi2 = mid; }
        cnts[tid] = lo2 - lo;
    }
    __syncthreads();
    for (int i = tid; i < 4096; i += 256) {
        int g = i >> 6;
        float c = (float)(cnts[g] > 0 ? cnts[g] : 1);
        gm[i] = pool[i] / c;
    }
    __syncthreads();
    for (int i = tid; i < 64 * 32; i += 256) {
        int g = i >> 5, j = i & 31;
        float acc = bc1[j];
        for (int k = 0; k < 64; ++k) acc += gm[g * 64 + k] * Wc1[k * 32 + j];
        am[i] = acc > 0.f ? acc : 0.f;
    }
    __syncthreads();
    if (tid < 128) {
        int g = tid >> 1, o = tid & 1;
        float acc = bc2[o];
        for (int j = 0; j < 32; ++j) acc += am[g * 32 + j] * Wc2[j * 2 + o];
        out[tid] = acc;
    }
}

extern "C" void kernel_launch(void* const* d_in, const int* in_sizes, int n_in,
                              void* d_out, int out_size, void* d_ws, size_t ws_size,
                              hipStream_t stream) {
    const float* x   = (const float*)d_in[0];
    const void* edge = d_in[1];     // int32 or int64, auto-detected
    const void* batch = d_in[2];
    const float* W1l = (const float*)d_in[3];
    const float* b1  = (const float*)d_in[4];
    const float* W1r = (const float*)d_in[5];
    const float* W2l = (const float*)d_in[6];
    const float* b2  = (const float*)d_in[7];
    const float* W2r = (const float*)d_in[8];
    const float* W3l = (const float*)d_in[9];
    const float* b3  = (const float*)d_in[10];
    const float* W3r = (const float*)d_in[11];
    const float* Wc1 = (const float*)d_in[12];
    const float* bc1 = (const float*)d_in[13];
    const float* Wc2 = (const float*)d_in[14];
    const float* bc2 = (const float*)d_in[15];

    const int n = in_sizes[0] / 64;   // 100000
    const int E = in_sizes[1] / 2;    // 1600000
    const int nb1 = (n + 511) >> 9;   // 196 coarse buckets (requires <= 256)
    const int NS = nb1 * NBLK1;       // scanned histogram length

    char* w = (char*)d_ws;
    size_t o = 0;
    auto take = [&](size_t bytes) -> void* {
        void* p = w + o;
        o = (o + bytes + 511) & ~(size_t)511;
        return p;
    };
    int* flag      = (int*)take(sizeof(int));
    u32* ticket    = (u32*)take(sizeof(u32));
    u32* offs      = (u32*)take((size_t)(n + 1) * sizeof(u32));
    u32* HG        = (u32*)take((size_t)(NS + 1) * sizeof(u32));
    u32* blockSums = (u32*)take(256 * sizeof(u32));
    u32* SB        = (u32*)take(256 * sizeof(u32));
    u32* P         = (u32*)take((size_t)E * sizeof(u32));
    int* ss        = (int*)take((size_t)E * sizeof(int));
    u16* Z         = (u16*)take((size_t)n * 64 * sizeof(u16));
    u16* R         = (u16*)take((size_t)n * 64 * sizeof(u16));
    u16* HA        = (u16*)take((size_t)n * 64 * sizeof(u16));
    u16* HB        = (u16*)take((size_t)n * 64 * sizeof(u16));
    float* pool    = (float*)take(64 * 64 * sizeof(float));

    init_detect<<<1, 256, 0, stream>>>((const int*)edge, flag, ticket, pool, E);

    // CSR build overlapped with layer-1 lift
    fused_hist_mm1<<<NBLK1 + MMBLK, 256, 0, stream>>>(edge, flag, HG, E, n, nb1,
                                                      x, W1l, W1r, b1, Z, R);
    const int nbScan = (NS + 2047) / 2048;
    scanAB<<<nbScan, 256, 0, stream>>>(HG, blockSums, SB, ticket, NS);
    p1_scatter<<<NBLK1, 256, 0, stream>>>(edge, flag, HG, SB, P, E, n, nb1);
    p2_kernel<<<nb1, 256, 0, stream>>>(P, HG, SB, offs, ss, E, n, nb1);

    const int nodeBlocks = (n + 3) / 4;
    agg_kernel<<<nodeBlocks, 256, 0, stream>>>(Z, R, offs, ss, HA, n);
    mm_mfma_kernel<<<MMBLK, 256, 0, stream>>>(HA, W2l, W2r, b2, Z, R, n);
    agg_kernel<<<nodeBlocks, 256, 0, stream>>>(Z, R, offs, ss, HB, n);
    mm_mfma_kernel<<<MMBLK, 256, 0, stream>>>(HB, W3l, W3r, b3, Z, R, n);
    agg_kernel<<<nodeBlocks, 256, 0, stream>>>(Z, R, offs, ss, HA, n);

    pool_kernel<<<(n + 255) / 256, 256, 0, stream>>>(HA, batch, flag, pool, n);
    head_kernel<<<1, 256, 0, stream>>>(pool, batch, flag, Wc1, bc1, Wc2, bc2,
                                       (float*)d_out, n);
}

// Round 9
// 334.615 us; speedup vs baseline: 2.9221x; 1.0564x over previous
//
#include <hip/hip_runtime.h>
#include <hip/hip_bf16.h>
#include <hip/hip_fp16.h>

typedef unsigned int u32;
typedef unsigned short u16;
typedef _Float16 f16x8 __attribute__((ext_vector_type(8)));
typedef float f32x4 __attribute__((ext_vector_type(4)));

#define NBLK1 512   // pass-1 blocks (edge chunks)
#define MMBLK 256   // mm blocks (1024 waves, ~6 tiles/wave: weight-frag setup amortized)

// ---------- fp16 pack/unpack ----------
__device__ __forceinline__ u16 f2h(float f) { return __half_as_ushort(__float2half(f)); }
__device__ __forceinline__ u32 packh2(float a, float b) {
    return (u32)f2h(a) | ((u32)f2h(b) << 16);
}
__device__ __forceinline__ __half2 sx(__half2 v, int m) {
    int iv = __shfl_xor(*(int*)&v, m, 64);
    return *(__half2*)&iv;
}

// ---------- int-width-agnostic index load (w64=1 -> int64 data on device) ----------
__device__ __forceinline__ int gidx(const void* p, long long i, int w64) {
    if (w64) return (int)((const long long*)p)[i];
    return ((const int*)p)[i];
}

// per-block int64 detection: probe 256 odd words in [0, 2E) (safe for int32 buffers;
// for int64 these are high halves of src values -> all zero). Same probe set in every
// block -> deterministic, L2-broadcast cheap.
__device__ __forceinline__ int detect_w64(const int* edge_words, int E, int tid, int* sh) {
    if (tid == 0) *sh = 0;
    __syncthreads();
    const long long totalWords = 2LL * E;
    const long long step = totalWords / 256;
    long long w = ((long long)tid * step) | 1;
    int nz = (w < totalWords) ? edge_words[w] : 0;
    if (nz) atomicOr(sh, 1);
    __syncthreads();
    return (*sh) ? 0 : 1;
}

// ---------- fused: p1_hist (blocks < NBLK1) + layer-1 MFMA lift (rest) ----------
__global__ void __launch_bounds__(256) fused_hist_mm1(
        const void* __restrict__ edge, int* __restrict__ flag, u32* __restrict__ ticket,
        u32* __restrict__ HG, int E, int n, int nb1,
        const float* __restrict__ X, const float* __restrict__ Wl,
        const float* __restrict__ Wr, const float* __restrict__ Bv,
        u16* __restrict__ Z, u16* __restrict__ R) {
    if (blockIdx.x < NBLK1) {
        __shared__ u32 h[256];
        __shared__ int shnz;
        const int tid = threadIdx.x;
        h[tid] = 0;
        const int w64 = detect_w64((const int*)edge, E, tid, &shnz);
        if (blockIdx.x == 0 && tid == 0) { flag[0] = w64; *ticket = 0; }
        __syncthreads();
        const int chunk = (E + NBLK1 - 1) / NBLK1;
        const int s = blockIdx.x * chunk;
        const int e = min(s + chunk, E);
        for (int i = s + tid; i < e; i += 256) {
            int d = gidx(edge, (long long)E + i, w64);
            if ((unsigned)d >= (unsigned)n) d = 0;
            atomicAdd(&h[d >> 9], 1);
        }
        __syncthreads();
        for (int b = tid; b < nb1; b += 256) HG[b * NBLK1 + blockIdx.x] = h[b];
        return;
    }
    // ---- MFMA lift, layer 1 (f32 input) ----
    const int lane = threadIdx.x & 63;
    const int quad = lane >> 4;
    const int m16 = lane & 15;
    f16x8 bl[2][4], br[2][4];
#pragma unroll
    for (int kh = 0; kh < 2; ++kh)
#pragma unroll
        for (int t = 0; t < 4; ++t)
#pragma unroll
            for (int j = 0; j < 8; ++j) {
                int k = kh * 32 + quad * 8 + j;
                int c = t * 16 + m16;
                bl[kh][t][j] = (_Float16)Wl[k * 64 + c];
                br[kh][t][j] = (_Float16)Wr[k * 64 + c];
            }
    float bias_t[4];
#pragma unroll
    for (int t = 0; t < 4; ++t) bias_t[t] = Bv[t * 16 + m16];

    const int ntiles = (n + 15) >> 4;
    const int nwaves = (gridDim.x - NBLK1) * 4;
    for (int tile = (blockIdx.x - NBLK1) * 4 + (threadIdx.x >> 6); tile < ntiles; tile += nwaves) {
        const int nodeBase = tile << 4;
        int nodeA = nodeBase + m16;
        if (nodeA >= n) nodeA = n - 1;
        f16x8 a[2];
#pragma unroll
        for (int kh = 0; kh < 2; ++kh) {
            const float4* p = (const float4*)(X + (size_t)nodeA * 64 + kh * 32 + quad * 8);
            float4 x0 = p[0], x1 = p[1];
            a[kh][0] = (_Float16)x0.x; a[kh][1] = (_Float16)x0.y;
            a[kh][2] = (_Float16)x0.z; a[kh][3] = (_Float16)x0.w;
            a[kh][4] = (_Float16)x1.x; a[kh][5] = (_Float16)x1.y;
            a[kh][6] = (_Float16)x1.z; a[kh][7] = (_Float16)x1.w;
        }
        f32x4 cl[4], cr[4];
#pragma unroll
        for (int t = 0; t < 4; ++t) {
            f32x4 c0 = {0.f, 0.f, 0.f, 0.f};
            c0 = __builtin_amdgcn_mfma_f32_16x16x32_f16(a[0], bl[0][t], c0, 0, 0, 0);
            c0 = __builtin_amdgcn_mfma_f32_16x16x32_f16(a[1], bl[1][t], c0, 0, 0, 0);
            cl[t] = c0;
            f32x4 c1 = {0.f, 0.f, 0.f, 0.f};
            c1 = __builtin_amdgcn_mfma_f32_16x16x32_f16(a[0], br[0][t], c1, 0, 0, 0);
            c1 = __builtin_amdgcn_mfma_f32_16x16x32_f16(a[1], br[1][t], c1, 0, 0, 0);
            cr[t] = c1;
        }
#pragma unroll
        for (int rg = 0; rg < 4; ++rg) {
            const int node = nodeBase + quad * 4 + rg;
            if (node < n) {
#pragma unroll
                for (int t = 0; t < 4; ++t) {
                    const int c = t * 16 + m16;
                    Z[(size_t)node * 64 + c] = f2h(cl[t][rg]);
                    R[(size_t)node * 64 + c] = f2h(cr[t][rg] + bias_t[t]);
                }
            }
        }
    }
}

// ---------- scanA with fused scanB (ticketed last block) ----------
__global__ void scanAB(u32* __restrict__ HG, u32* __restrict__ blockSums,
                       u32* __restrict__ SB, u32* __restrict__ ticket, int n) {
    __shared__ u32 ts[256];
    __shared__ int isLast;
    const int ITEMS = 8;
    const int tid = threadIdx.x;
    int base = blockIdx.x * 2048 + tid * ITEMS;
    u32 v[ITEMS];
    u32 sum = 0;
#pragma unroll
    for (int i = 0; i < ITEMS; ++i) {
        int idx = base + i;
        v[i] = (idx < n) ? HG[idx] : 0;
        sum += v[i];
    }
    ts[tid] = sum;
    __syncthreads();
    u32 incl = sum;
    for (int d = 1; d < 256; d <<= 1) {
        u32 y = 0;
        if (tid >= d) y = ts[tid - d];
        __syncthreads();
        incl += y;
        ts[tid] = incl;
        __syncthreads();
    }
    u32 run = incl - sum;
#pragma unroll
    for (int i = 0; i < ITEMS; ++i) {
        int idx = base + i;
        if (idx < n) HG[idx] = run;
        run += v[i];
    }
    if (tid == 255) {
        atomicExch(&blockSums[blockIdx.x], incl);
        __threadfence();
        u32 t = atomicAdd(ticket, 1);
        isLast = (t == gridDim.x - 1);
    }
    __syncthreads();
    if (!isLast) return;
    const int nb = gridDim.x;
    u32 bv = (tid < nb) ? atomicAdd(&blockSums[tid], 0u) : 0;
    ts[tid] = bv;
    __syncthreads();
    u32 bincl = bv;
    for (int d = 1; d < 256; d <<= 1) {
        u32 y = 0;
        if (tid >= d) y = ts[tid - d];
        __syncthreads();
        bincl += y;
        ts[tid] = bincl;
        __syncthreads();
    }
    if (tid < nb) SB[tid] = bincl - bv;
}

// ---------- pass 1b: rank via LDS atomics; write packed (dst&511)<<17|src ----------
__global__ void __launch_bounds__(256) p1_scatter(const void* __restrict__ edge,
                                                  const int* __restrict__ flag,
                                                  const u32* __restrict__ HG,
                                                  const u32* __restrict__ SB,
                                                  u32* __restrict__ P, int E, int n, int nb1) {
    __shared__ u32 base[256];
    __shared__ u32 cur[256];
    const int tid = threadIdx.x;
    cur[tid] = 0;
    for (int b = tid; b < nb1; b += 256) {
        int i = b * NBLK1 + blockIdx.x;
        base[b] = HG[i] + SB[i >> 11];
    }
    __syncthreads();
    const int w64 = flag[0];
    const int chunk = (E + NBLK1 - 1) / NBLK1;
    const int s = blockIdx.x * chunk;
    const int e = min(s + chunk, E);
    for (int i = s + tid; i < e; i += 256) {
        int d = gidx(edge, (long long)E + i, w64);
        if ((unsigned)d >= (unsigned)n) d = 0;
        int sv = gidx(edge, i, w64);
        if ((unsigned)sv >= (unsigned)n) sv = 0;
        const int b1 = d >> 9;
        u32 r = atomicAdd(&cur[b1], 1);
        P[base[b1] + r] = (u32)sv | ((u32)(d & 511) << 17);
    }
}

// ---------- pass 2: per coarse bucket — fine hist(512), LDS scan, offs + final ss ----------
// block 0 also zero-inits pool (consumed much later by pool_kernel)
__global__ void __launch_bounds__(256) p2_kernel(const u32* __restrict__ P,
                                                 const u32* __restrict__ HG,
                                                 const u32* __restrict__ SB,
                                                 u32* __restrict__ offs,
                                                 int* __restrict__ ss,
                                                 float* __restrict__ pool,
                                                 int E, int n, int nb1) {
    __shared__ u32 h2[512];
    __shared__ u32 ts[256];
    const int tid = threadIdx.x;
    const int b = blockIdx.x;
    if (b == 0)
        for (int i = tid; i < 4096; i += 256) pool[i] = 0.f;
    const int i0 = b * NBLK1;
    const int bs = (int)(HG[i0] + SB[i0 >> 11]);
    int be;
    if (b + 1 < nb1) {
        const int i1 = (b + 1) * NBLK1;
        be = (int)(HG[i1] + SB[i1 >> 11]);
    } else be = E;
    h2[tid] = 0;
    h2[tid + 256] = 0;
    __syncthreads();
    for (int i = bs + tid; i < be; i += 256) atomicAdd(&h2[(P[i] >> 17) & 511], 1);
    __syncthreads();
    u32 v0 = h2[2 * tid], v1 = h2[2 * tid + 1];
    u32 sum = v0 + v1;
    ts[tid] = sum;
    __syncthreads();
    u32 incl = sum;
    for (int d = 1; d < 256; d <<= 1) {
        u32 y = 0;
        if (tid >= d) y = ts[tid - d];
        __syncthreads();
        incl += y;
        ts[tid] = incl;
        __syncthreads();
    }
    u32 run = incl - sum;
    h2[2 * tid] = run;
    h2[2 * tid + 1] = run + v0;
    const int node0 = b * 512 + 2 * tid;
    if (node0 < n) offs[node0] = bs + run;
    if (node0 + 1 < n) offs[node0 + 1] = bs + run + v0;
    if (b == 0 && tid == 0) offs[n] = (u32)E;
    __syncthreads();
    for (int i = bs + tid; i < be; i += 256) {
        u32 p = P[i];
        u32 r = atomicAdd(&h2[(p >> 17) & 511], 1);
        ss[bs + r] = (int)(p & 0x1FFFFu);
    }
}

// ---------- MFMA lift (layers 2,3): Z = X@Wl (f16), R = X@Wr + b (f16) ----------
__global__ void __launch_bounds__(256) mm_mfma_kernel(const u16* __restrict__ X,
                                                      const float* __restrict__ Wl,
                                                      const float* __restrict__ Wr,
                                                      const float* __restrict__ Bv,
                                                      u16* __restrict__ Z,
                                                      u16* __restrict__ R, int n) {
    const int lane = threadIdx.x & 63;
    const int quad = lane >> 4;
    const int m16 = lane & 15;
    f16x8 bl[2][4], br[2][4];
#pragma unroll
    for (int kh = 0; kh < 2; ++kh)
#pragma unroll
        for (int t = 0; t < 4; ++t)
#pragma unroll
            for (int j = 0; j < 8; ++j) {
                int k = kh * 32 + quad * 8 + j;
                int c = t * 16 + m16;
                bl[kh][t][j] = (_Float16)Wl[k * 64 + c];
                br[kh][t][j] = (_Float16)Wr[k * 64 + c];
            }
    float bias_t[4];
#pragma unroll
    for (int t = 0; t < 4; ++t) bias_t[t] = Bv[t * 16 + m16];

    const int ntiles = (n + 15) >> 4;
    const int nwaves = gridDim.x * 4;
    for (int tile = blockIdx.x * 4 + (threadIdx.x >> 6); tile < ntiles; tile += nwaves) {
        const int nodeBase = tile << 4;
        int nodeA = nodeBase + m16;
        if (nodeA >= n) nodeA = n - 1;
        const _Float16* xp = (const _Float16*)X + (size_t)nodeA * 64;
        f16x8 a[2];
#pragma unroll
        for (int kh = 0; kh < 2; ++kh)
            a[kh] = *(const f16x8*)(xp + kh * 32 + quad * 8);
        f32x4 cl[4], cr[4];
#pragma unroll
        for (int t = 0; t < 4; ++t) {
            f32x4 c0 = {0.f, 0.f, 0.f, 0.f};
            c0 = __builtin_amdgcn_mfma_f32_16x16x32_f16(a[0], bl[0][t], c0, 0, 0, 0);
            c0 = __builtin_amdgcn_mfma_f32_16x16x32_f16(a[1], bl[1][t], c0, 0, 0, 0);
            cl[t] = c0;
            f32x4 c1 = {0.f, 0.f, 0.f, 0.f};
            c1 = __builtin_amdgcn_mfma_f32_16x16x32_f16(a[0], br[0][t], c1, 0, 0, 0);
            c1 = __builtin_amdgcn_mfma_f32_16x16x32_f16(a[1], br[1][t], c1, 0, 0, 0);
            cr[t] = c1;
        }
#pragma unroll
        for (int rg = 0; rg < 4; ++rg) {
            const int node = nodeBase + quad * 4 + rg;
            if (node < n) {
#pragma unroll
                for (int t = 0; t < 4; ++t) {
                    const int c = t * 16 + m16;
                    Z[(size_t)node * 64 + c] = f2h(cl[t][rg]);
                    R[(size_t)node * 64 + c] = f2h(cr[t][rg] + bias_t[t]);
                }
            }
        }
    }
}

// ---------- aggregation: packed-f16, dwordx2 loads, 16-neighbor groups (4 loads in flight) ----
__global__ void __launch_bounds__(256) agg_kernel(const u16* __restrict__ Zin,
                                                  const u16* __restrict__ Rin,
                                                  const u32* __restrict__ offs,
                                                  const int* __restrict__ ss,
                                                  u16* __restrict__ Hout, int n) {
    const int lane = threadIdx.x & 63;
    const int q = lane >> 4;       // quarter handles rows j == q (mod 4)
    const int sub = lane & 15;     // 8-byte word-pair within a 128 B row
    const u32* Z32 = (const u32*)Zin;
    const int node = (blockIdx.x << 2) | (threadIdx.x >> 6);
    if (node >= n) return;
    const int off = (int)offs[node], end = (int)offs[node + 1];
    const int deg = end - off;
    const __half2 zero2 = __float2half2_rn(0.f);
    const __half2 one2 = __float2half2_rn(1.f);
    __half2 a0 = zero2, a1 = zero2, b0 = zero2, b1 = zero2;
    __half2 c0 = zero2, c1 = zero2, d0 = zero2, d1 = zero2;
    for (int base = off; base < end; base += 64) {
        const int cnt = min(64, end - base);
        const int idx = ss[base + (lane < cnt ? lane : cnt - 1)];
        int p = 0;
        for (; p + 16 <= cnt; p += 16) {
            int j0 = p + q;
            int s0 = __shfl(idx, j0, 64);
            int s1 = __shfl(idx, j0 + 4, 64);
            int s2 = __shfl(idx, j0 + 8, 64);
            int s3 = __shfl(idx, j0 + 12, 64);
            uint2 u0 = *(const uint2*)(Z32 + s0 * 32 + 2 * sub);
            uint2 u1 = *(const uint2*)(Z32 + s1 * 32 + 2 * sub);
            uint2 u2 = *(const uint2*)(Z32 + s2 * 32 + 2 * sub);
            uint2 u3 = *(const uint2*)(Z32 + s3 * 32 + 2 * sub);
            a0 = __hadd2(a0, *(const __half2*)&u0.x);
            a1 = __hadd2(a1, *(const __half2*)&u0.y);
            b0 = __hadd2(b0, *(const __half2*)&u1.x);
            b1 = __hadd2(b1, *(const __half2*)&u1.y);
            c0 = __hadd2(c0, *(const __half2*)&u2.x);
            c1 = __hadd2(c1, *(const __half2*)&u2.y);
            d0 = __hadd2(d0, *(const __half2*)&u3.x);
            d1 = __hadd2(d1, *(const __half2*)&u3.y);
        }
        const int rem = cnt - p;   // 0..15
        if (rem) {
            int j = p + q, j1 = p + 4 + q;
            int s0 = __shfl(idx, j < cnt ? j : cnt - 1, 64);
            int s1 = __shfl(idx, j1 < cnt ? j1 : cnt - 1, 64);
            uint2 u0 = *(const uint2*)(Z32 + s0 * 32 + 2 * sub);
            uint2 u1 = *(const uint2*)(Z32 + s1 * 32 + 2 * sub);
            __half2 m0 = (j < cnt) ? one2 : zero2;
            __half2 m1 = (j1 < cnt) ? one2 : zero2;
            a0 = __hfma2(*(const __half2*)&u0.x, m0, a0);
            a1 = __hfma2(*(const __half2*)&u0.y, m0, a1);
            b0 = __hfma2(*(const __half2*)&u1.x, m1, b0);
            b1 = __hfma2(*(const __half2*)&u1.y, m1, b1);
            if (rem > 8) {
                int j2 = p + 8 + q, j3 = p + 12 + q;
                int s2 = __shfl(idx, j2 < cnt ? j2 : cnt - 1, 64);
                int s3 = __shfl(idx, j3 < cnt ? j3 : cnt - 1, 64);
                uint2 u2 = *(const uint2*)(Z32 + s2 * 32 + 2 * sub);
                uint2 u3 = *(const uint2*)(Z32 + s3 * 32 + 2 * sub);
                __half2 m2 = (j2 < cnt) ? one2 : zero2;
                __half2 m3 = (j3 < cnt) ? one2 : zero2;
                c0 = __hfma2(*(const __half2*)&u2.x, m2, c0);
                c1 = __hfma2(*(const __half2*)&u2.y, m2, c1);
                d0 = __hfma2(*(const __half2*)&u3.x, m3, d0);
                d1 = __hfma2(*(const __half2*)&u3.y, m3, d1);
            }
        }
    }
    a0 = __hadd2(__hadd2(a0, b0), __hadd2(c0, d0));
    a1 = __hadd2(__hadd2(a1, b1), __hadd2(c1, d1));
    a0 = __hadd2(a0, sx(a0, 16)); a0 = __hadd2(a0, sx(a0, 32));
    a1 = __hadd2(a1, sx(a1, 16)); a1 = __hadd2(a1, sx(a1, 32));
    if (q == 0) {
        const u32* R32 = (const u32*)Rin;
        uint2 rr = *(const uint2*)(R32 + node * 32 + 2 * sub);
        const float rd = deg > 0 ? 1.f / (float)deg : 0.f;
        float2 s01 = __half22float2(a0);
        float2 s23 = __half22float2(a1);
        float2 r01 = __half22float2(*(const __half2*)&rr.x);
        float2 r23 = __half22float2(*(const __half2*)&rr.y);
        uint2 outp;
        outp.x = packh2(fmaxf(fmaf(s01.x, rd, r01.x), 0.f),
                        fmaxf(fmaf(s01.y, rd, r01.y), 0.f));
        outp.y = packh2(fmaxf(fmaf(s23.x, rd, r23.x), 0.f),
                        fmaxf(fmaf(s23.y, rd, r23.y), 0.f));
        *(uint2*)(((u32*)Hout) + node * 32 + 2 * sub) = outp;
    }
}

// ---------- global mean pool (batch sorted): 64 rows/wave ----------
__global__ void pool_kernel(const u16* __restrict__ H, const void* __restrict__ batch,
                            const int* __restrict__ flag, float* __restrict__ pool, int n) {
    const int lane = threadIdx.x & 63;
    const int wave = threadIdx.x >> 6;
    int start = (blockIdx.x * 4 + wave) * 64;
    int end = min(start + 64, n);
    if (start >= end) return;
    const int w64 = flag[0];
    float acc = 0.f;
    int cur = gidx(batch, start, w64) & 63;
    for (int i = start; i < end; ++i) {
        int g = gidx(batch, i, w64) & 63;
        if (g != cur) {
            atomicAdd(&pool[cur * 64 + lane], acc);
            acc = 0.f;
            cur = g;
        }
        acc += __half2float(__ushort_as_half(H[i * 64 + lane]));
    }
    atomicAdd(&pool[cur * 64 + lane], acc);
}

// ---------- head MLP: out = relu(g@Wc1+bc1)@Wc2 + bc2 ----------
__global__ void head_kernel(const float* __restrict__ pool, const void* __restrict__ batch,
                            const int* __restrict__ flag,
                            const float* __restrict__ Wc1, const float* __restrict__ bc1,
                            const float* __restrict__ Wc2, const float* __restrict__ bc2,
                            float* __restrict__ out, int n) {
    __shared__ float gm[64 * 64];
    __shared__ float am[64 * 32];
    __shared__ int cnts[64];
    const int tid = threadIdx.x;  // 256
    const int w64 = flag[0];
    if (tid < 64) {
        int lo = 0, hi = n;
        while (lo < hi) { int mid = (lo + hi) >> 1; if (gidx(batch, mid, w64) < tid) lo = mid + 1; else hi = mid; }
        int lo2 = 0, hi2 = n;
        int v2 = tid + 1;
        while (lo2 < hi2) { int mid = (lo2 + hi2) >> 1; if (gidx(batch, mid, w64) < v2) lo2 = mid + 1; else hi2 = mid; }
        cnts[tid] = lo2 - lo;
    }
    __syncthreads();
    for (int i = tid; i < 4096; i += 256) {
        int g = i >> 6;
        float c = (float)(cnts[g] > 0 ? cnts[g] : 1);
        gm[i] = pool[i] / c;
    }
    __syncthreads();
    for (int i = tid; i < 64 * 32; i += 256) {
        int g = i >> 5, j = i & 31;
        float acc = bc1[j];
        for (int k = 0; k < 64; ++k) acc += gm[g * 64 + k] * Wc1[k * 32 + j];
        am[i] = acc > 0.f ? acc : 0.f;
    }
    __syncthreads();
    if (tid < 128) {
        int g = tid >> 1, o = tid & 1;
        float acc = bc2[o];
        for (int j = 0; j < 32; ++j) acc += am[g * 32 + j] * Wc2[j * 2 + o];
        out[tid] = acc;
    }
}

extern "C" void kernel_launch(void* const* d_in, const int* in_sizes, int n_in,
                              void* d_out, int out_size, void* d_ws, size_t ws_size,
                              hipStream_t stream) {
    const float* x   = (const float*)d_in[0];
    const void* edge = d_in[1];     // int32 or int64, auto-detected
    const void* batch = d_in[2];
    const float* W1l = (const float*)d_in[3];
    const float* b1  = (const float*)d_in[4];
    const float* W1r = (const float*)d_in[5];
    const float* W2l = (const float*)d_in[6];
    const float* b2  = (const float*)d_in[7];
    const float* W2r = (const float*)d_in[8];
    const float* W3l = (const float*)d_in[9];
    const float* b3  = (const float*)d_in[10];
    const float* W3r = (const float*)d_in[11];
    const float* Wc1 = (const float*)d_in[12];
    const float* bc1 = (const float*)d_in[13];
    const float* Wc2 = (const float*)d_in[14];
    const float* bc2 = (const float*)d_in[15];

    const int n = in_sizes[0] / 64;   // 100000
    const int E = in_sizes[1] / 2;    // 1600000
    const int nb1 = (n + 511) >> 9;   // 196 coarse buckets (requires <= 256)
    const int NS = nb1 * NBLK1;       // scanned histogram length

    char* w = (char*)d_ws;
    size_t o = 0;
    auto take = [&](size_t bytes) -> void* {
        void* p = w + o;
        o = (o + bytes + 511) & ~(size_t)511;
        return p;
    };
    int* flag      = (int*)take(sizeof(int));
    u32* ticket    = (u32*)take(sizeof(u32));
    u32* offs      = (u32*)take((size_t)(n + 1) * sizeof(u32));
    u32* HG        = (u32*)take((size_t)(NS + 1) * sizeof(u32));
    u32* blockSums = (u32*)take(256 * sizeof(u32));
    u32* SB        = (u32*)take(256 * sizeof(u32));
    u32* P         = (u32*)take((size_t)E * sizeof(u32));
    int* ss        = (int*)take((size_t)E * sizeof(int));
    u16* Z         = (u16*)take((size_t)n * 64 * sizeof(u16));
    u16* R         = (u16*)take((size_t)n * 64 * sizeof(u16));
    u16* HA        = (u16*)take((size_t)n * 64 * sizeof(u16));
    u16* HB        = (u16*)take((size_t)n * 64 * sizeof(u16));
    float* pool    = (float*)take(64 * 64 * sizeof(float));

    // CSR hist + layer-1 lift in one launch (also writes flag/ticket)
    fused_hist_mm1<<<NBLK1 + MMBLK, 256, 0, stream>>>(edge, flag, ticket, HG, E, n, nb1,
                                                      x, W1l, W1r, b1, Z, R);
    const int nbScan = (NS + 2047) / 2048;
    scanAB<<<nbScan, 256, 0, stream>>>(HG, blockSums, SB, ticket, NS);
    p1_scatter<<<NBLK1, 256, 0, stream>>>(edge, flag, HG, SB, P, E, n, nb1);
    p2_kernel<<<nb1, 256, 0, stream>>>(P, HG, SB, offs, ss, pool, E, n, nb1);

    const int nodeBlocks = (n + 3) / 4;
    agg_kernel<<<nodeBlocks, 256, 0, stream>>>(Z, R, offs, ss, HA, n);
    mm_mfma_kernel<<<MMBLK, 256, 0, stream>>>(HA, W2l, W2r, b2, Z, R, n);
    agg_kernel<<<nodeBlocks, 256, 0, stream>>>(Z, R, offs, ss, HB, n);
    mm_mfma_kernel<<<MMBLK, 256, 0, stream>>>(HB, W3l, W3r, b3, Z, R, n);
    agg_kernel<<<nodeBlocks, 256, 0, stream>>>(Z, R, offs, ss, HA, n);

    pool_kernel<<<(n + 255) / 256, 256, 0, stream>>>(HA, batch, flag, pool, n);
    head_kernel<<<1, 256, 0, stream>>>(pool, batch, flag, Wc1, bc1, Wc2, bc2,
                                       (float*)d_out, n);
}